// Round 4
// baseline (1032.938 us; speedup 1.0000x reference)
//
#include <hip/hip_runtime.h>

typedef __bf16 bf16;
typedef __bf16 bf16x8 __attribute__((ext_vector_type(8)));
typedef __bf16 bf16x4 __attribute__((ext_vector_type(4)));
typedef float  f32x4  __attribute__((ext_vector_type(4)));

// Problem constants: B=32, N=1024, DIM=1152, H=12, KV=4, D=96, G=3, P=3, LS=32

static __device__ __forceinline__ float load_any(const void* p, size_t i, int isbf) {
  return isbf ? (float)((const bf16*)p)[i] : ((const float*)p)[i];
}

// async global->LDS, 16 bytes per lane. LDS dest is wave-uniform base + lane*16.
static __device__ __forceinline__ void cp16(const bf16* g, bf16* l) {
  __builtin_amdgcn_global_load_lds(
      (const __attribute__((address_space(1))) void*)g,
      (__attribute__((address_space(3))) void*)l, 16, 0, 0);
}

// ---------------- dtype detect ----------------
__global__ void k_detect(const unsigned int* __restrict__ x, int* __restrict__ flag) {
  __shared__ int cnt[256];
  unsigned int w = x[(size_t)threadIdx.x * 65536u + 123u];
  unsigned int lo = w & 0xffffu;
  int e = (int)((lo >> 7) & 0xffu);
  cnt[threadIdx.x] = (lo == 0u) || (e >= 100 && e <= 140);
  __syncthreads();
  for (int s = 128; s > 0; s >>= 1) {
    if ((int)threadIdx.x < s) cnt[threadIdx.x] += cnt[threadIdx.x + s];
    __syncthreads();
  }
  if (threadIdx.x == 0) *flag = (cnt[0] >= 128) ? 1 : 0;
}

// ---------------- small params -> fp32; zero focus accumulators ----------------
// pbuf: [0,1152) wq_b | [1152,1920) wkv_b | [1920,5376) dwc_w | [5376,5760) dwc_b
//       | [5760,6912) proj_b | [6912,10368) dwc_w transposed tap-major [9][384]
__global__ void k_prep(const void* wq_b, const void* wkv_b, const void* dwc_w,
                       const void* dwc_b, const void* proj_b,
                       float* __restrict__ pbuf, float* __restrict__ acc,
                       const int* __restrict__ flagp) {
  int isbf = *flagp;
  int i = blockIdx.x * 256 + threadIdx.x;
  if (i < 1024) acc[i] = 0.f;
  if (i >= 10368) return;
  float v;
  if (i < 1152)      v = load_any(wq_b,   i,        isbf);
  else if (i < 1920) v = load_any(wkv_b,  i - 1152, isbf);
  else if (i < 5376) v = load_any(dwc_w,  i - 1920, isbf);
  else if (i < 5760) v = load_any(dwc_b,  i - 5376, isbf);
  else if (i < 6912) v = load_any(proj_b, i - 5760, isbf);
  else {
    int r = i - 6912, tap = r / 384, c = r - tap * 384;
    v = load_any(dwc_w, (size_t)c * 9 + tap, isbf);
  }
  pbuf[i] = v;
}

// ---------------- weight transpose -> bf16 [out][in], zero-pads out rows [C,Cpad) ----------------
__global__ __launch_bounds__(256) void k_transpose(const void* __restrict__ in,
    bf16* __restrict__ out, int R, int C, int Cpad, const int* __restrict__ flagp) {
  int isbf = *flagp;
  __shared__ bf16 tile[32][33];
  int c0 = blockIdx.x * 32, r0 = blockIdx.y * 32;
  int tx = threadIdx.x & 31, ty = threadIdx.x >> 5;
  for (int i = ty; i < 32; i += 8) {
    int r = r0 + i, c = c0 + tx;
    float v = (r < R && c < C) ? load_any(in, (size_t)r * C + c, isbf) : 0.f;
    tile[i][tx] = (bf16)v;
  }
  __syncthreads();
  for (int i = ty; i < 32; i += 8) {
    int c = c0 + i, r = r0 + tx;
    if (c < Cpad && r < R) out[(size_t)c * R + r] = tile[tx][i];
  }
}

// ---------------- x ingest -> bf16 (fp32 mode only) ----------------
__global__ void k_ingest(const void* __restrict__ x, bf16* __restrict__ xb,
                         const int* __restrict__ flagp) {
  if (*flagp) return;
  size_t i = ((size_t)blockIdx.x * 256 + threadIdx.x) * 8;
  if (i >= (size_t)37748736) return;
  const float4* xf = (const float4*)((const float*)x + i);
  float4 a = xf[0], b = xf[1];
  bf16x8 o = {(bf16)a.x, (bf16)a.y, (bf16)a.z, (bf16)a.w,
              (bf16)b.x, (bf16)b.y, (bf16)b.z, (bf16)b.w};
  *(bf16x8*)(xb + i) = o;
}

// ---------------- 256x256 8-phase MFMA GEMM (T1+T2+T3+T4+T5) ----------------
// C[M,Nreal] = A[M,K] @ Bt[Npad,K]^T + bias, stores masked col<Nreal.
// 512 threads = 8 waves (2 M-halves x 4 N-quarters). BK=64, double-buffered
// 128KB LDS. Per tile: 4 phases, each {stage 2 chunks | ds_read quadrant |
// setprio(1) 16 MFMA setprio(0) | counted vmcnt + s_barrier}.
// Wait ledger (per wave, 8 staged chunks/tile: A r0-3 @P1/P2, B r0-3 @P3/P4):
//   tile-end  vmcnt(2): covers next tile's A r0-3 + B r0,r1 (qn0 class)
//   P2-end    vmcnt(4): covers this tile's B r2,r3 (qn1 class)
// B chunk->wave map interleaves qn0/qn1 classes so r0,r1 are exactly the
// chunks any wave's P1 read needs. LDS XOR-swizzle (byte bits 5,4 ^= bits
// 9,10 = row bits 2,3) applied on pre-swizzled global source AND ds_read
// addr (involution, rule #21). Prologue drains lgkmcnt(0) once so the fsh
// zero-init ds_write is committed before any raw s_barrier.
#define SWZB(q) ((q) ^ ((((q) >> 9) & 1) << 5) ^ ((((q) >> 10) & 1) << 4))

__global__ __launch_bounds__(512, 2) void k_gemm8(const bf16* __restrict__ A,
    const bf16* __restrict__ Aalt, int asel,
    const bf16* __restrict__ Bt, const float* __restrict__ bias,
    void* __restrict__ Cv, int M, int Npad, int Nreal, int K, int ldc,
    int out_mode, int focus, float* __restrict__ facc,
    const int* __restrict__ flagp) {
  __shared__ __align__(16) bf16 sA[2][256 * 64];
  __shared__ __align__(16) bf16 sB[2][256 * 64];
  __shared__ float fsh[8];
  const int t = threadIdx.x;
  const int NTN = Npad >> 8;
  const int nwg = gridDim.x;                       // % 8 == 0
  const int wg = ((int)blockIdx.x & 7) * (nwg >> 3) + ((int)blockIdx.x >> 3);
  const int n0 = (wg % NTN) << 8;
  const int m0 = (wg / NTN) << 8;
  const int wid = t >> 6, lane = t & 63, quad = lane >> 4, l16 = lane & 15;
  const int g = wid >> 2;                          // A-half / wave row group
  const int wn = (wid & 3) << 6;                   // wave col base in tile
  const int flg = *flagp;
  const bf16* Asrc = (asel && flg) ? Aalt : A;
  if (t < 8) fsh[t] = 0.f;

  f32x4 acc[8][4];
  f32x4 zero = {0.f, 0.f, 0.f, 0.f};
#pragma unroll
  for (int i = 0; i < 8; i++)
#pragma unroll
    for (int j = 0; j < 4; j++) acc[i][j] = zero;

#define STAGE_A(r, bufv, k0v) do {                                         \
    int c_ = g * 16 + (wid & 3) * 4 + (r);                                 \
    int srow_ = c_ * 8 + (lane >> 3);                                      \
    int gcol_ = ((lane & 7) * 8) ^ (((srow_ >> 2) & 1) << 4)               \
                                 ^ (((srow_ >> 3) & 1) << 3);              \
    cp16(Asrc + (size_t)(m0 + srow_) * K + (k0v) + gcol_,                  \
         &sA[bufv][c_ * 512 + lane * 8]); } while (0)

#define STAGE_B(r, bufv, k0v) do {                                         \
    int c_ = ((r) < 2) ? ((wid >> 1) * 8 + (wid & 1) * 2 + (r))            \
                       : ((wid >> 1) * 8 + 4 + (wid & 1) * 2 + (r) - 2);   \
    int srow_ = c_ * 8 + (lane >> 3);                                      \
    int gcol_ = ((lane & 7) * 8) ^ (((srow_ >> 2) & 1) << 4)               \
                                 ^ (((srow_ >> 3) & 1) << 3);              \
    cp16(Bt + (size_t)(n0 + srow_) * K + (k0v) + gcol_,                    \
         &sB[bufv][c_ * 512 + lane * 8]); } while (0)

#define LDA_Q(dst, qm) do {                                                \
    _Pragma("unroll") for (int i_ = 0; i_ < 4; i_++)                       \
    _Pragma("unroll") for (int ks_ = 0; ks_ < 2; ks_++) {                  \
      int q_ = (g * 128 + (qm) * 64 + i_ * 16 + l16) * 128                 \
               + ks_ * 64 + quad * 16;                                     \
      dst[i_][ks_] = *(const bf16x8*)(sAc + SWZB(q_)); } } while (0)

#define LDB_Q(qn) do {                                                     \
    _Pragma("unroll") for (int j_ = 0; j_ < 2; j_++)                       \
    _Pragma("unroll") for (int ks_ = 0; ks_ < 2; ks_++) {                  \
      int q_ = (wn + (qn) * 32 + j_ * 16 + l16) * 128                      \
               + ks_ * 64 + quad * 16;                                     \
      bfr[j_][ks_] = *(const bf16x8*)(sBc + SWZB(q_)); } } while (0)

#define MMAQ(src, qm, qn) do {                                             \
    _Pragma("unroll") for (int ks_ = 0; ks_ < 2; ks_++)                    \
    _Pragma("unroll") for (int i_ = 0; i_ < 4; i_++)                       \
    _Pragma("unroll") for (int j_ = 0; j_ < 2; j_++)                       \
      acc[(qm) * 4 + i_][(qn) * 2 + j_] =                                  \
        __builtin_amdgcn_mfma_f32_16x16x32_bf16(src[i_][ks_], bfr[j_][ks_],\
          acc[(qm) * 4 + i_][(qn) * 2 + j_], 0, 0, 0); } while (0)

#define BAR asm volatile("s_barrier" ::: "memory")

  // prologue: stage tile 0 (ledger order A r0-3, B r0-3); cover A+Bqn0;
  // lgkmcnt(0) commits the fsh zero-init before the first raw barrier.
  STAGE_A(0, 0, 0); STAGE_A(1, 0, 0); STAGE_A(2, 0, 0); STAGE_A(3, 0, 0);
  STAGE_B(0, 0, 0); STAGE_B(1, 0, 0); STAGE_B(2, 0, 0); STAGE_B(3, 0, 0);
  asm volatile("s_waitcnt vmcnt(2) lgkmcnt(0)\ns_barrier" ::: "memory");

  bf16x8 afr0[4][2], afr1[4][2], bfr[2][2];
  const int NT = K >> 6;                 // 18 for K=1152
  int ks0 = 64;
  int cur = 0;
  for (int tile = 0; tile < NT; ++tile) {
    const char* sAc = (const char*)&sA[cur][0];
    const char* sBc = (const char*)&sB[cur][0];
    const int nb = cur ^ 1;
    const bool stg = (tile < NT - 1);
    // P1: quadrant (qm0, qn0); reads 8A+4B; stages next A r0,r1
    if (stg) { STAGE_A(0, nb, ks0); STAGE_A(1, nb, ks0); }
    LDA_Q(afr0, 0); LDB_Q(0);
    __builtin_amdgcn_s_setprio(1); MMAQ(afr0, 0, 0); __builtin_amdgcn_s_setprio(0);
    BAR;
    // P2: (qm1, qn0); reads 8A; stages next A r2,r3; end-wait covers B qn1
    if (stg) { STAGE_A(2, nb, ks0); STAGE_A(3, nb, ks0); }
    LDA_Q(afr1, 1);
    __builtin_amdgcn_s_setprio(1); MMAQ(afr1, 1, 0); __builtin_amdgcn_s_setprio(0);
    if (stg) asm volatile("s_waitcnt vmcnt(4)\ns_barrier" ::: "memory");
    else     asm volatile("s_waitcnt vmcnt(0)\ns_barrier" ::: "memory");
    // P3: (qm1, qn1); reads 4B; stages next B r0,r1
    if (stg) { STAGE_B(0, nb, ks0); STAGE_B(1, nb, ks0); }
    LDB_Q(1);
    __builtin_amdgcn_s_setprio(1); MMAQ(afr1, 1, 1); __builtin_amdgcn_s_setprio(0);
    BAR;
    // P4: (qm0, qn1); no LDS reads; stages next B r2,r3; end-wait covers
    // next tile's A r0-3 + B r0,r1
    if (stg) { STAGE_B(2, nb, ks0); STAGE_B(3, nb, ks0); }
    __builtin_amdgcn_s_setprio(1); MMAQ(afr0, 0, 1); __builtin_amdgcn_s_setprio(0);
    if (stg) asm volatile("s_waitcnt vmcnt(2)\ns_barrier" ::: "memory");
    else     BAR;
    if (stg) ks0 += 64;
    cur ^= 1;
  }

  // ---------------- epilogue: bias, store (masked), fused focus sums ----------------
  const bool obf = (out_mode != 0) && (flg != 0);
#pragma unroll
  for (int J = 0; J < 4; J++) {
    int col = n0 + wn + J * 16 + l16;
    float s2 = 0.f, s6 = 0.f;
    if (col < Nreal) {
      float bv = bias[col];
#pragma unroll
      for (int I = 0; I < 8; I++) {
#pragma unroll
        for (int r = 0; r < 4; r++) {
          int row = m0 + g * 128 + I * 16 + quad * 4 + r;
          float v = acc[I][J][r] + bv;
          if (obf) ((bf16*)Cv)[(size_t)row * ldc + col] = (bf16)v;
          else     ((float*)Cv)[(size_t)row * ldc + col] = v;
          float tt = fmaxf(v, 0.f);
          float t2 = tt * tt;
          s2 += t2; s6 += t2 * t2 * t2;
        }
      }
    }
    if (focus) {
      int h = col / 96;            // uniform per fragment (16 | 96)
      if (h < 16) {
#pragma unroll
        for (int m = 1; m < 64; m <<= 1) {
          s2 += __shfl_xor(s2, m);
          s6 += __shfl_xor(s6, m);
        }
        if (lane == 0) {
          int slot = h - n0 / 96;  // block spans <=4 heads
          atomicAdd(&fsh[slot * 2],     s2);
          atomicAdd(&fsh[slot * 2 + 1], s6);
        }
      }
    }
  }
  if (focus) {
    __syncthreads();
    if (t < 4) {
      int h0 = n0 / 96;
      int h = h0 + t;
      int hmax = (n0 + 255) / 96;
      if (h <= hmax && h < 16) {
        int b = m0 >> 10;
        int gdx = (h < 12) ? (b * 12 + h) : (384 + b * 4 + (h - 12));
        atomicAdd(&facc[gdx * 2],     fsh[t * 2]);
        atomicAdd(&facc[gdx * 2 + 1], fsh[t * 2 + 1]);
      }
    }
  }
#undef STAGE_A
#undef STAGE_B
#undef LDA_Q
#undef LDB_Q
#undef MMAQ
#undef BAR
}

// focus stage 2: scale[g] = sqrt(s2/s6)
__global__ void k_scales(const float* __restrict__ acc, float* __restrict__ scale) {
  int i = blockIdx.x * 256 + threadIdx.x;
  if (i < 512) scale[i] = sqrtf(acc[i * 2] / acc[i * 2 + 1]);
}

// ---------------- kv einsum, split-K partials (k,v from fused C, ldc=1920) ----------------
__global__ __launch_bounds__(256) void k_kvein_part(const float* __restrict__ Cq,
    float* __restrict__ part) {
  int blk = blockIdx.x;                 // g*8 + c
  int g = blk >> 3, c = blk & 7;
  const float* kbase = Cq + (size_t)(g >> 2) * 1024 * 1920 + 1152 + (g & 3) * 96
                     + (size_t)c * 128 * 1920;
  const float* vbase = kbase + 384;
  __shared__ float sk[32][96];
  __shared__ float sv[32][96];
  int ty = threadIdx.x >> 4, tx = threadIdx.x & 15;
  float acc[6][6];
#pragma unroll
  for (int i = 0; i < 6; i++)
#pragma unroll
    for (int j = 0; j < 6; j++) acc[i][j] = 0.f;
  for (int nc = 0; nc < 128; nc += 32) {
    __syncthreads();
    for (int i = threadIdx.x; i < 32 * 24; i += 256) {
      int n = i / 24, d4 = (i - n * 24) * 4;
      float4 kk = *(const float4*)(kbase + (size_t)(nc + n) * 1920 + d4);
      float4 vv = *(const float4*)(vbase + (size_t)(nc + n) * 1920 + d4);
      float tv;
      tv = fmaxf(kk.x, 0.f); sk[n][d4 + 0] = tv * tv * tv;
      tv = fmaxf(kk.y, 0.f); sk[n][d4 + 1] = tv * tv * tv;
      tv = fmaxf(kk.z, 0.f); sk[n][d4 + 2] = tv * tv * tv;
      tv = fmaxf(kk.w, 0.f); sk[n][d4 + 3] = tv * tv * tv;
      sv[n][d4 + 0] = vv.x; sv[n][d4 + 1] = vv.y;
      sv[n][d4 + 2] = vv.z; sv[n][d4 + 3] = vv.w;
    }
    __syncthreads();
#pragma unroll 4
    for (int n = 0; n < 32; n++) {
      float kr[6], vr[6];
#pragma unroll
      for (int i = 0; i < 6; i++) kr[i] = sk[n][ty * 6 + i];
#pragma unroll
      for (int j = 0; j < 6; j++) vr[j] = sv[n][tx * 6 + j];
#pragma unroll
      for (int i = 0; i < 6; i++)
#pragma unroll
        for (int j = 0; j < 6; j++) acc[i][j] += kr[i] * vr[j];
    }
  }
  float* out = part + (size_t)blk * 9216;
#pragma unroll
  for (int i = 0; i < 6; i++)
#pragma unroll
    for (int j = 0; j < 6; j++)
      out[(ty * 6 + i) * 96 + tx * 6 + j] = acc[i][j];   // [dk][e]
}

// reduce 8 partials, scale, store transposed bf16: KVT[g][e][dk]
__global__ void k_kvred(const float* __restrict__ part, const float* __restrict__ sck,
                        bf16* __restrict__ KVT) {
  int t = blockIdx.x * 256 + threadIdx.x;   // over 128*9216
  if (t >= 1179648) return;
  int g = t / 9216, r = t - g * 9216;
  int dk = r / 96, e = r - dk * 96;
  const float* p = part + (size_t)g * 8 * 9216 + r;
  float s = 0.f;
#pragma unroll
  for (int c = 0; c < 8; c++) s += p[(size_t)c * 9216];
  KVT[(size_t)g * 9216 + e * 96 + dk] = (bf16)(sck[g] * s);
}

// ---------------- depthwise 3x3 conv, float4-vectorized ----------------
__global__ void k_dwc(const float* __restrict__ Cq, const float* __restrict__ pwt,
                      const float* __restrict__ pb, bf16* __restrict__ VD) {
  int idx = blockIdx.x * 256 + threadIdx.x;            // [B][KV][1024][24] float4 groups
  if (idx >= 32 * 4 * 1024 * 24) return;
  int g4 = idx % 24;
  int n  = (idx / 24) & 1023;
  int kv = (idx / (24 * 1024)) & 3;
  int b  = idx / (24 * 1024 * 4);
  int y = n >> 5, x = n & 31;
  int c0 = kv * 96 + g4 * 4;
  float4 acc = *(const float4*)(pb + c0);
  const float* vb = Cq + (size_t)b * 1024 * 1920 + 1536 + c0;
#pragma unroll
  for (int dy = -1; dy <= 1; dy++) {
    int yy = y + dy;
    if (yy < 0 || yy >= 32) continue;
#pragma unroll
    for (int dx = -1; dx <= 1; dx++) {
      int xx = x + dx;
      if (xx < 0 || xx >= 32) continue;
      float4 wv = *(const float4*)(pwt + ((dy + 1) * 3 + (dx + 1)) * 384 + c0);
      float4 vv = *(const float4*)(vb + (size_t)((yy << 5) + xx) * 1920);
      acc.x += wv.x * vv.x; acc.y += wv.y * vv.y;
      acc.z += wv.z * vv.z; acc.w += wv.w * vv.w;
    }
  }
  bf16x4 o = {(bf16)acc.x, (bf16)acc.y, (bf16)acc.z, (bf16)acc.w};
  *(bf16x4*)(VD + (size_t)idx * 4) = o;
}

// ---------------- attn: OC = focus(q) @ kv[h%4] + vdwc[h%4] ----------------
__global__ __launch_bounds__(256) void k_attn(const float* __restrict__ Cq,
    const float* __restrict__ scq, const bf16* __restrict__ KVT,
    const bf16* __restrict__ VD, bf16* __restrict__ OC) {
  int bh = blockIdx.x;
  int b = bh / 12, h = bh - b * 12;
  int kvh = h & 3;
  int n0 = blockIdx.y * 64;
  __shared__ bf16 sQ[64][104];
  __shared__ bf16 sKV[96][104];
  int t = threadIdx.x;
  float sc = scq[b * 12 + h];
  const float* qsrc = Cq + (size_t)(b * 1024 + n0) * 1920 + h * 96;
  for (int i = t; i < 64 * 24; i += 256) {
    int row = i / 24, seg = (i - row * 24) * 4;
    float4 q4 = *(const float4*)(qsrc + (size_t)row * 1920 + seg);
    bf16x4 o;
    float tv;
    tv = fmaxf(q4.x, 0.f); o[0] = (bf16)(sc * tv * tv * tv);
    tv = fmaxf(q4.y, 0.f); o[1] = (bf16)(sc * tv * tv * tv);
    tv = fmaxf(q4.z, 0.f); o[2] = (bf16)(sc * tv * tv * tv);
    tv = fmaxf(q4.w, 0.f); o[3] = (bf16)(sc * tv * tv * tv);
    *(bf16x4*)&sQ[row][seg] = o;
  }
  const bf16* kvsrc = KVT + (size_t)(b * 4 + kvh) * 9216;
  for (int i = t; i < 96 * 12; i += 256) {
    int row = i / 12, seg = (i - row * 12) * 8;
    *(bf16x8*)&sKV[row][seg] = *(const bf16x8*)(kvsrc + row * 96 + seg);
  }
  __syncthreads();
  int wave = t >> 6, lane = t & 63, quad = lane >> 4, l16 = lane & 15;
  f32x4 acc[6];
  f32x4 zero = {0.f, 0.f, 0.f, 0.f};
#pragma unroll
  for (int j = 0; j < 6; j++) acc[j] = zero;
#pragma unroll
  for (int k0 = 0; k0 < 96; k0 += 32) {
    bf16x8 a = *(const bf16x8*)&sQ[wave * 16 + l16][k0 + quad * 8];
#pragma unroll
    for (int j = 0; j < 6; j++) {
      bf16x8 bb = *(const bf16x8*)&sKV[j * 16 + l16][k0 + quad * 8];
      acc[j] = __builtin_amdgcn_mfma_f32_16x16x32_bf16(a, bb, acc[j], 0, 0, 0);
    }
  }
  const bf16* vd = VD + ((size_t)(b * 4 + kvh) * 1024 + n0) * 96;
  bf16* oc = OC + (size_t)(b * 1024 + n0) * 1152 + h * 96;
#pragma unroll
  for (int j = 0; j < 6; j++) {
    int col = j * 16 + l16;
#pragma unroll
    for (int r = 0; r < 4; r++) {
      int row = wave * 16 + quad * 4 + r;
      float v = acc[j][r] + (float)vd[(size_t)row * 96 + col];
      oc[(size_t)row * 1152 + col] = (bf16)v;
    }
  }
}

// ---------------- launch ----------------
extern "C" void kernel_launch(void* const* d_in, const int* in_sizes, int n_in,
                              void* d_out, int out_size, void* d_ws, size_t ws_size,
                              hipStream_t stream) {
  (void)in_sizes; (void)n_in; (void)out_size; (void)ws_size;
  const void* x      = d_in[0];
  const void* wq_w   = d_in[1];
  const void* wq_b   = d_in[2];
  const void* wkv_w  = d_in[3];
  const void* wkv_b  = d_in[4];
  const void* dwc_w  = d_in[5];
  const void* dwc_b  = d_in[6];
  const void* proj_w = d_in[7];
  const void* proj_b = d_in[8];

  char* ws = (char*)d_ws;
  size_t off = 0;
  auto alloc = [&](size_t bytes) -> void* {
    void* p = ws + off;
    off = (off + bytes + 255) & ~(size_t)255;
    return p;
  };
  int*   flag   = (int*)  alloc(256);
  float* pbuf   = (float*)alloc((size_t)10368 * 4);
  float* facc   = (float*)alloc(1024 * 4);               // 512 groups x (s2,s6)
  float* scale  = (float*)alloc(512 * 4);                // [0,384) q | [384,512) k
  bf16*  wcat_t = (bf16*) alloc((size_t)2048 * 1152 * 2);// [wq_t; wkv_t; zero-pad]
  bf16*  proj_t = (bf16*) alloc((size_t)1280 * 1152 * 2);// proj_t + zero-pad rows
  bf16*  xb     = (bf16*) alloc((size_t)37748736 * 2);   // x bf16; reused: kv partials, out_comb
  float* cq     = (float*)alloc((size_t)32768 * 1920 * 4); // fused q|k|v fp32
  bf16*  kvt    = (bf16*) alloc((size_t)128 * 9216 * 2);
  bf16*  vdwc   = (bf16*) alloc((size_t)32 * 4 * 1024 * 96 * 2);
  // part aliases xb: x-bf16 content is dead after the fused GEMM's last read,
  // and k_kvred finishes reading part before k_attn writes out_comb into xb.
  float* part   = (float*)xb;                            // 37.75 MB < 75.5 MB

  k_detect<<<1, 256, 0, stream>>>((const unsigned int*)x, flag);
  k_prep<<<41, 256, 0, stream>>>(wq_b, wkv_b, dwc_w, dwc_b, proj_b, pbuf, facc, flag);
  // wq -> wcat rows [0,1152); wkv -> rows [1152,1920); zero-pad rows [1920,2048)
  k_transpose<<<dim3(36, 36), 256, 0, stream>>>(wq_w, wcat_t, 1152, 1152, 1152, flag);
  k_transpose<<<dim3(28, 36), 256, 0, stream>>>(wkv_w, wcat_t + (size_t)1152 * 1152,
                                                1152, 768, 896, flag);
  k_transpose<<<dim3(40, 36), 256, 0, stream>>>(proj_w, proj_t, 1152, 1152, 1280, flag);
  k_ingest<<<18432, 256, 0, stream>>>(x, xb, flag);

  const bf16* xbf = (const bf16*)x;

  // fused [q | kv] = x @ [wq | wkv] + b, fp32 out, focus sums fused in epilogue
  k_gemm8<<<1024, 512, 0, stream>>>(xb, xbf, 1, wcat_t, pbuf + 0, (void*)cq,
                                    32768, 2048, 1920, 1152, 1920, 0, 1, facc, flag);
  k_scales<<<2, 256, 0, stream>>>(facc, scale);

  k_kvein_part<<<1024, 256, 0, stream>>>(cq, part);
  k_kvred<<<4608, 256, 0, stream>>>(part, scale + 384, kvt);

  k_dwc<<<12288, 256, 0, stream>>>(cq, pbuf + 6912, pbuf + 5376, vdwc);
  k_attn<<<dim3(384, 16), 256, 0, stream>>>(cq, scale, kvt, vdwc, xb /* out_comb */);

  // final: out = out_comb @ proj + b -> d_out (dtype per flag), cols masked <1152
  k_gemm8<<<640, 512, 0, stream>>>(xb, nullptr, 0, proj_t, pbuf + 5760, d_out,
                                   32768, 1280, 1152, 1152, 1152, 1, 0, facc, flag);
}

// Round 5
// 896.089 us; speedup vs baseline: 1.1527x; 1.1527x over previous
//
#include <hip/hip_runtime.h>

typedef __bf16 bf16;
typedef __bf16 bf16x8 __attribute__((ext_vector_type(8)));
typedef __bf16 bf16x4 __attribute__((ext_vector_type(4)));
typedef float  f32x4  __attribute__((ext_vector_type(4)));

// Problem constants: B=32, N=1024, DIM=1152, H=12, KV=4, D=96, G=3, P=3, LS=32

static __device__ __forceinline__ float load_any(const void* p, size_t i, int isbf) {
  return isbf ? (float)((const bf16*)p)[i] : ((const float*)p)[i];
}

// async global->LDS, 16 bytes per lane. LDS dest is wave-uniform base + lane*16.
static __device__ __forceinline__ void cp16(const bf16* g, bf16* l) {
  __builtin_amdgcn_global_load_lds(
      (const __attribute__((address_space(1))) void*)g,
      (__attribute__((address_space(3))) void*)l, 16, 0, 0);
}

// ---------------- dtype detect ----------------
__global__ void k_detect(const unsigned int* __restrict__ x, int* __restrict__ flag) {
  __shared__ int cnt[256];
  unsigned int w = x[(size_t)threadIdx.x * 65536u + 123u];
  unsigned int lo = w & 0xffffu;
  int e = (int)((lo >> 7) & 0xffu);
  cnt[threadIdx.x] = (lo == 0u) || (e >= 100 && e <= 140);
  __syncthreads();
  for (int s = 128; s > 0; s >>= 1) {
    if ((int)threadIdx.x < s) cnt[threadIdx.x] += cnt[threadIdx.x + s];
    __syncthreads();
  }
  if (threadIdx.x == 0) *flag = (cnt[0] >= 128) ? 1 : 0;
}

// ---------------- small params -> fp32; zero focus accumulators ----------------
// pbuf: [0,1152) wq_b | [1152,1920) wkv_b | [1920,5376) dwc_w | [5376,5760) dwc_b
//       | [5760,6912) proj_b | [6912,10368) dwc_w transposed tap-major [9][384]
__global__ void k_prep(const void* wq_b, const void* wkv_b, const void* dwc_w,
                       const void* dwc_b, const void* proj_b,
                       float* __restrict__ pbuf, float* __restrict__ acc,
                       const int* __restrict__ flagp) {
  int isbf = *flagp;
  int i = blockIdx.x * 256 + threadIdx.x;
  if (i < 1024) acc[i] = 0.f;
  if (i >= 10368) return;
  float v;
  if (i < 1152)      v = load_any(wq_b,   i,        isbf);
  else if (i < 1920) v = load_any(wkv_b,  i - 1152, isbf);
  else if (i < 5376) v = load_any(dwc_w,  i - 1920, isbf);
  else if (i < 5760) v = load_any(dwc_b,  i - 5376, isbf);
  else if (i < 6912) v = load_any(proj_b, i - 5760, isbf);
  else {
    int r = i - 6912, tap = r / 384, c = r - tap * 384;
    v = load_any(dwc_w, (size_t)c * 9 + tap, isbf);
  }
  pbuf[i] = v;
}

// ---------------- weight transpose -> bf16 [out][in], zero-pads out rows [C,Cpad) ----------------
__global__ __launch_bounds__(256) void k_transpose(const void* __restrict__ in,
    bf16* __restrict__ out, int R, int C, int Cpad, const int* __restrict__ flagp) {
  int isbf = *flagp;
  __shared__ bf16 tile[32][33];
  int c0 = blockIdx.x * 32, r0 = blockIdx.y * 32;
  int tx = threadIdx.x & 31, ty = threadIdx.x >> 5;
  for (int i = ty; i < 32; i += 8) {
    int r = r0 + i, c = c0 + tx;
    float v = (r < R && c < C) ? load_any(in, (size_t)r * C + c, isbf) : 0.f;
    tile[i][tx] = (bf16)v;
  }
  __syncthreads();
  for (int i = ty; i < 32; i += 8) {
    int c = c0 + i, r = r0 + tx;
    if (c < Cpad && r < R) out[(size_t)c * R + r] = tile[tx][i];
  }
}

// ---------------- x ingest -> bf16 (fp32 mode only) ----------------
__global__ void k_ingest(const void* __restrict__ x, bf16* __restrict__ xb,
                         const int* __restrict__ flagp) {
  if (*flagp) return;
  size_t i = ((size_t)blockIdx.x * 256 + threadIdx.x) * 8;
  if (i >= (size_t)37748736) return;
  const float4* xf = (const float4*)((const float*)x + i);
  float4 a = xf[0], b = xf[1];
  bf16x8 o = {(bf16)a.x, (bf16)a.y, (bf16)a.z, (bf16)a.w,
              (bf16)b.x, (bf16)b.y, (bf16)b.z, (bf16)b.w};
  *(bf16x8*)(xb + i) = o;
}

// ---------------- 256x256 8-phase MFMA GEMM (T1+T2+T3+T4+T5) ----------------
// C[M,Nreal] = A[M,K] @ Bt[Npad,K]^T + bias, stores masked col<Nreal.
// 512 threads = 8 waves (2 M-halves x 4 N-quarters). BK=64, double-buffered
// 128KB LDS. Per tile: 4 phases, each {stage 2 chunks | ds_read quadrant |
// setprio(1) 16 MFMA setprio(0) | counted vmcnt + s_barrier}.
// Wait ledger (per wave, 8 staged chunks/tile: A r0-3 @P1/P2, B r0-3 @P3/P4):
//   tile-end  vmcnt(2): covers next tile's A r0-3 + B r0,r1 (qn0 class)
//   P2-end    vmcnt(4): covers this tile's B r2,r3 (qn1 class)
// B chunk->wave map interleaves qn0/qn1 classes so r0,r1 are exactly the
// chunks any wave's P1 read needs.
// LDS swizzle (R3 POSTMORTEM FIX): rows are 128B = exactly one bank period,
// so byte bits 6:4 must be XOR'd with 3 row bits: off ^= (row&7)<<4. Then a
// wave's 64 b128 lanes spread 8 lanes per 16B slot = hardware minimum.
// (R3's 2-bit swizzle left offset bits 5:4 = quad^sw -> 16-way conflict,
// 4.25e7 SQ_LDS_BANK_CONFLICT.) Applied on pre-swizzled GLOBAL source
// (element ^= (srow&7)<<3, stays within the same 128B window so coalescing
// holds) AND on the ds_read byte address — same involution (rule #21).
__global__ __launch_bounds__(512, 2) void k_gemm8(const bf16* __restrict__ A,
    const bf16* __restrict__ Aalt, int asel,
    const bf16* __restrict__ Bt, const float* __restrict__ bias,
    void* __restrict__ Cv, int M, int Npad, int Nreal, int K, int ldc,
    int out_mode, int focus, float* __restrict__ facc,
    const int* __restrict__ flagp) {
  __shared__ __align__(16) bf16 sA[2][256 * 64];
  __shared__ __align__(16) bf16 sB[2][256 * 64];
  __shared__ float fsh[8];
  const int t = threadIdx.x;
  const int NTN = Npad >> 8;
  const int nwg = gridDim.x;                       // % 8 == 0
  const int wg = ((int)blockIdx.x & 7) * (nwg >> 3) + ((int)blockIdx.x >> 3);
  const int n0 = (wg % NTN) << 8;
  const int m0 = (wg / NTN) << 8;
  const int wid = t >> 6, lane = t & 63, quad = lane >> 4, l16 = lane & 15;
  const int g = wid >> 2;                          // A-half / wave row group
  const int wn = (wid & 3) << 6;                   // wave col base in tile
  const int swl = (l16 & 7) << 4;                  // read-side swizzle bits
  const int flg = *flagp;
  const bf16* Asrc = (asel && flg) ? Aalt : A;
  if (t < 8) fsh[t] = 0.f;

  f32x4 acc[8][4];
  f32x4 zero = {0.f, 0.f, 0.f, 0.f};
#pragma unroll
  for (int i = 0; i < 8; i++)
#pragma unroll
    for (int j = 0; j < 4; j++) acc[i][j] = zero;

#define STAGE_A(r, bufv, k0v) do {                                         \
    int c_ = g * 16 + (wid & 3) * 4 + (r);                                 \
    int srow_ = c_ * 8 + (lane >> 3);                                      \
    int gcol_ = ((lane & 7) * 8) ^ ((srow_ & 7) << 3);                     \
    cp16(Asrc + (size_t)(m0 + srow_) * K + (k0v) + gcol_,                  \
         &sA[bufv][c_ * 512 + lane * 8]); } while (0)

#define STAGE_B(r, bufv, k0v) do {                                         \
    int c_ = ((r) < 2) ? ((wid >> 1) * 8 + (wid & 1) * 2 + (r))            \
                       : ((wid >> 1) * 8 + 4 + (wid & 1) * 2 + (r) - 2);   \
    int srow_ = c_ * 8 + (lane >> 3);                                      \
    int gcol_ = ((lane & 7) * 8) ^ ((srow_ & 7) << 3);                     \
    cp16(Bt + (size_t)(n0 + srow_) * K + (k0v) + gcol_,                    \
         &sB[bufv][c_ * 512 + lane * 8]); } while (0)

#define LDA_Q(dst, qm) do {                                                \
    _Pragma("unroll") for (int i_ = 0; i_ < 4; i_++)                       \
    _Pragma("unroll") for (int ks_ = 0; ks_ < 2; ks_++) {                  \
      int row_ = g * 128 + (qm) * 64 + i_ * 16 + l16;                      \
      int q_ = row_ * 128 + ((ks_ * 64 + quad * 16) ^ swl);                \
      dst[i_][ks_] = *(const bf16x8*)(sAc + q_); } } while (0)

#define LDB_Q(qn) do {                                                     \
    _Pragma("unroll") for (int j_ = 0; j_ < 2; j_++)                       \
    _Pragma("unroll") for (int ks_ = 0; ks_ < 2; ks_++) {                  \
      int row_ = wn + (qn) * 32 + j_ * 16 + l16;                           \
      int q_ = row_ * 128 + ((ks_ * 64 + quad * 16) ^ swl);                \
      bfr[j_][ks_] = *(const bf16x8*)(sBc + q_); } } while (0)

#define MMAQ(src, qm, qn) do {                                             \
    _Pragma("unroll") for (int ks_ = 0; ks_ < 2; ks_++)                    \
    _Pragma("unroll") for (int i_ = 0; i_ < 4; i_++)                       \
    _Pragma("unroll") for (int j_ = 0; j_ < 2; j_++)                       \
      acc[(qm) * 4 + i_][(qn) * 2 + j_] =                                  \
        __builtin_amdgcn_mfma_f32_16x16x32_bf16(src[i_][ks_], bfr[j_][ks_],\
          acc[(qm) * 4 + i_][(qn) * 2 + j_], 0, 0, 0); } while (0)

#define BAR asm volatile("s_barrier" ::: "memory")

  // prologue: stage tile 0 (ledger order A r0-3, B r0-3); cover A+Bqn0;
  // lgkmcnt(0) commits the fsh zero-init before the first raw barrier.
  STAGE_A(0, 0, 0); STAGE_A(1, 0, 0); STAGE_A(2, 0, 0); STAGE_A(3, 0, 0);
  STAGE_B(0, 0, 0); STAGE_B(1, 0, 0); STAGE_B(2, 0, 0); STAGE_B(3, 0, 0);
  asm volatile("s_waitcnt vmcnt(2) lgkmcnt(0)\ns_barrier" ::: "memory");

  bf16x8 afr0[4][2], afr1[4][2], bfr[2][2];
  const int NT = K >> 6;                 // 18 for K=1152
  int ks0 = 64;
  int cur = 0;
  for (int tile = 0; tile < NT; ++tile) {
    const char* sAc = (const char*)&sA[cur][0];
    const char* sBc = (const char*)&sB[cur][0];
    const int nb = cur ^ 1;
    const bool stg = (tile < NT - 1);
    // P1: quadrant (qm0, qn0); reads 8A+4B; stages next A r0,r1
    if (stg) { STAGE_A(0, nb, ks0); STAGE_A(1, nb, ks0); }
    LDA_Q(afr0, 0); LDB_Q(0);
    __builtin_amdgcn_s_setprio(1); MMAQ(afr0, 0, 0); __builtin_amdgcn_s_setprio(0);
    BAR;
    // P2: (qm1, qn0); reads 8A; stages next A r2,r3; end-wait covers B qn1
    if (stg) { STAGE_A(2, nb, ks0); STAGE_A(3, nb, ks0); }
    LDA_Q(afr1, 1);
    __builtin_amdgcn_s_setprio(1); MMAQ(afr1, 1, 0); __builtin_amdgcn_s_setprio(0);
    if (stg) asm volatile("s_waitcnt vmcnt(4)\ns_barrier" ::: "memory");
    else     asm volatile("s_waitcnt vmcnt(0)\ns_barrier" ::: "memory");
    // P3: (qm1, qn1); reads 4B; stages next B r0,r1
    if (stg) { STAGE_B(0, nb, ks0); STAGE_B(1, nb, ks0); }
    LDB_Q(1);
    __builtin_amdgcn_s_setprio(1); MMAQ(afr1, 1, 1); __builtin_amdgcn_s_setprio(0);
    BAR;
    // P4: (qm0, qn1); no LDS reads; stages next B r2,r3; end-wait covers
    // next tile's A r0-3 + B r0,r1
    if (stg) { STAGE_B(2, nb, ks0); STAGE_B(3, nb, ks0); }
    __builtin_amdgcn_s_setprio(1); MMAQ(afr0, 0, 1); __builtin_amdgcn_s_setprio(0);
    if (stg) asm volatile("s_waitcnt vmcnt(2)\ns_barrier" ::: "memory");
    else     BAR;
    if (stg) ks0 += 64;
    cur ^= 1;
  }

  // ---------------- epilogue: bias, store (masked), fused focus sums ----------------
  const bool obf = (out_mode != 0) && (flg != 0);
#pragma unroll
  for (int J = 0; J < 4; J++) {
    int col = n0 + wn + J * 16 + l16;
    float s2 = 0.f, s6 = 0.f;
    if (col < Nreal) {
      float bv = bias[col];
#pragma unroll
      for (int I = 0; I < 8; I++) {
#pragma unroll
        for (int r = 0; r < 4; r++) {
          int row = m0 + g * 128 + I * 16 + quad * 4 + r;
          float v = acc[I][J][r] + bv;
          if (obf) ((bf16*)Cv)[(size_t)row * ldc + col] = (bf16)v;
          else     ((float*)Cv)[(size_t)row * ldc + col] = v;
          float tt = fmaxf(v, 0.f);
          float t2 = tt * tt;
          s2 += t2; s6 += t2 * t2 * t2;
        }
      }
    }
    if (focus) {
      int h = col / 96;            // uniform per fragment (16 | 96)
      if (h < 16) {
#pragma unroll
        for (int m = 1; m < 64; m <<= 1) {
          s2 += __shfl_xor(s2, m);
          s6 += __shfl_xor(s6, m);
        }
        if (lane == 0) {
          int slot = h - n0 / 96;  // block spans <=4 heads
          atomicAdd(&fsh[slot * 2],     s2);
          atomicAdd(&fsh[slot * 2 + 1], s6);
        }
      }
    }
  }
  if (focus) {
    __syncthreads();
    if (t < 4) {
      int h0 = n0 / 96;
      int h = h0 + t;
      int hmax = (n0 + 255) / 96;
      if (h <= hmax && h < 16) {
        int b = m0 >> 10;
        int gdx = (h < 12) ? (b * 12 + h) : (384 + b * 4 + (h - 12));
        atomicAdd(&facc[gdx * 2],     fsh[t * 2]);
        atomicAdd(&facc[gdx * 2 + 1], fsh[t * 2 + 1]);
      }
    }
  }
#undef STAGE_A
#undef STAGE_B
#undef LDA_Q
#undef LDB_Q
#undef MMAQ
#undef BAR
}

// focus stage 2: scale[g] = sqrt(s2/s6)
__global__ void k_scales(const float* __restrict__ acc, float* __restrict__ scale) {
  int i = blockIdx.x * 256 + threadIdx.x;
  if (i < 512) scale[i] = sqrtf(acc[i * 2] / acc[i * 2 + 1]);
}

// ---------------- kv einsum, split-K partials (k,v from fused C, ldc=1920) ----------------
__global__ __launch_bounds__(256) void k_kvein_part(const float* __restrict__ Cq,
    float* __restrict__ part) {
  int blk = blockIdx.x;                 // g*8 + c
  int g = blk >> 3, c = blk & 7;
  const float* kbase = Cq + (size_t)(g >> 2) * 1024 * 1920 + 1152 + (g & 3) * 96
                     + (size_t)c * 128 * 1920;
  const float* vbase = kbase + 384;
  __shared__ float sk[32][96];
  __shared__ float sv[32][96];
  int ty = threadIdx.x >> 4, tx = threadIdx.x & 15;
  float acc[6][6];
#pragma unroll
  for (int i = 0; i < 6; i++)
#pragma unroll
    for (int j = 0; j < 6; j++) acc[i][j] = 0.f;
  for (int nc = 0; nc < 128; nc += 32) {
    __syncthreads();
    for (int i = threadIdx.x; i < 32 * 24; i += 256) {
      int n = i / 24, d4 = (i - n * 24) * 4;
      float4 kk = *(const float4*)(kbase + (size_t)(nc + n) * 1920 + d4);
      float4 vv = *(const float4*)(vbase + (size_t)(nc + n) * 1920 + d4);
      float tv;
      tv = fmaxf(kk.x, 0.f); sk[n][d4 + 0] = tv * tv * tv;
      tv = fmaxf(kk.y, 0.f); sk[n][d4 + 1] = tv * tv * tv;
      tv = fmaxf(kk.z, 0.f); sk[n][d4 + 2] = tv * tv * tv;
      tv = fmaxf(kk.w, 0.f); sk[n][d4 + 3] = tv * tv * tv;
      sv[n][d4 + 0] = vv.x; sv[n][d4 + 1] = vv.y;
      sv[n][d4 + 2] = vv.z; sv[n][d4 + 3] = vv.w;
    }
    __syncthreads();
#pragma unroll 4
    for (int n = 0; n < 32; n++) {
      float kr[6], vr[6];
#pragma unroll
      for (int i = 0; i < 6; i++) kr[i] = sk[n][ty * 6 + i];
#pragma unroll
      for (int j = 0; j < 6; j++) vr[j] = sv[n][tx * 6 + j];
#pragma unroll
      for (int i = 0; i < 6; i++)
#pragma unroll
        for (int j = 0; j < 6; j++) acc[i][j] += kr[i] * vr[j];
    }
  }
  float* out = part + (size_t)blk * 9216;
#pragma unroll
  for (int i = 0; i < 6; i++)
#pragma unroll
    for (int j = 0; j < 6; j++)
      out[(ty * 6 + i) * 96 + tx * 6 + j] = acc[i][j];   // [dk][e]
}

// reduce 8 partials, scale, store transposed bf16: KVT[g][e][dk]
__global__ void k_kvred(const float* __restrict__ part, const float* __restrict__ sck,
                        bf16* __restrict__ KVT) {
  int t = blockIdx.x * 256 + threadIdx.x;   // over 128*9216
  if (t >= 1179648) return;
  int g = t / 9216, r = t - g * 9216;
  int dk = r / 96, e = r - dk * 96;
  const float* p = part + (size_t)g * 8 * 9216 + r;
  float s = 0.f;
#pragma unroll
  for (int c = 0; c < 8; c++) s += p[(size_t)c * 9216];
  KVT[(size_t)g * 9216 + e * 96 + dk] = (bf16)(sck[g] * s);
}

// ---------------- depthwise 3x3 conv, float4-vectorized ----------------
__global__ void k_dwc(const float* __restrict__ Cq, const float* __restrict__ pwt,
                      const float* __restrict__ pb, bf16* __restrict__ VD) {
  int idx = blockIdx.x * 256 + threadIdx.x;            // [B][KV][1024][24] float4 groups
  if (idx >= 32 * 4 * 1024 * 24) return;
  int g4 = idx % 24;
  int n  = (idx / 24) & 1023;
  int kv = (idx / (24 * 1024)) & 3;
  int b  = idx / (24 * 1024 * 4);
  int y = n >> 5, x = n & 31;
  int c0 = kv * 96 + g4 * 4;
  float4 acc = *(const float4*)(pb + c0);
  const float* vb = Cq + (size_t)b * 1024 * 1920 + 1536 + c0;
#pragma unroll
  for (int dy = -1; dy <= 1; dy++) {
    int yy = y + dy;
    if (yy < 0 || yy >= 32) continue;
#pragma unroll
    for (int dx = -1; dx <= 1; dx++) {
      int xx = x + dx;
      if (xx < 0 || xx >= 32) continue;
      float4 wv = *(const float4*)(pwt + ((dy + 1) * 3 + (dx + 1)) * 384 + c0);
      float4 vv = *(const float4*)(vb + (size_t)((yy << 5) + xx) * 1920);
      acc.x += wv.x * vv.x; acc.y += wv.y * vv.y;
      acc.z += wv.z * vv.z; acc.w += wv.w * vv.w;
    }
  }
  bf16x4 o = {(bf16)acc.x, (bf16)acc.y, (bf16)acc.z, (bf16)acc.w};
  *(bf16x4*)(VD + (size_t)idx * 4) = o;
}

// ---------------- attn: OC = focus(q) @ kv[h%4] + vdwc[h%4] ----------------
__global__ __launch_bounds__(256) void k_attn(const float* __restrict__ Cq,
    const float* __restrict__ scq, const bf16* __restrict__ KVT,
    const bf16* __restrict__ VD, bf16* __restrict__ OC) {
  int bh = blockIdx.x;
  int b = bh / 12, h = bh - b * 12;
  int kvh = h & 3;
  int n0 = blockIdx.y * 64;
  __shared__ bf16 sQ[64][104];
  __shared__ bf16 sKV[96][104];
  int t = threadIdx.x;
  float sc = scq[b * 12 + h];
  const float* qsrc = Cq + (size_t)(b * 1024 + n0) * 1920 + h * 96;
  for (int i = t; i < 64 * 24; i += 256) {
    int row = i / 24, seg = (i - row * 24) * 4;
    float4 q4 = *(const float4*)(qsrc + (size_t)row * 1920 + seg);
    bf16x4 o;
    float tv;
    tv = fmaxf(q4.x, 0.f); o[0] = (bf16)(sc * tv * tv * tv);
    tv = fmaxf(q4.y, 0.f); o[1] = (bf16)(sc * tv * tv * tv);
    tv = fmaxf(q4.z, 0.f); o[2] = (bf16)(sc * tv * tv * tv);
    tv = fmaxf(q4.w, 0.f); o[3] = (bf16)(sc * tv * tv * tv);
    *(bf16x4*)&sQ[row][seg] = o;
  }
  const bf16* kvsrc = KVT + (size_t)(b * 4 + kvh) * 9216;
  for (int i = t; i < 96 * 12; i += 256) {
    int row = i / 12, seg = (i - row * 12) * 8;
    *(bf16x8*)&sKV[row][seg] = *(const bf16x8*)(kvsrc + row * 96 + seg);
  }
  __syncthreads();
  int wave = t >> 6, lane = t & 63, quad = lane >> 4, l16 = lane & 15;
  f32x4 acc[6];
  f32x4 zero = {0.f, 0.f, 0.f, 0.f};
#pragma unroll
  for (int j = 0; j < 6; j++) acc[j] = zero;
#pragma unroll
  for (int k0 = 0; k0 < 96; k0 += 32) {
    bf16x8 a = *(const bf16x8*)&sQ[wave * 16 + l16][k0 + quad * 8];
#pragma unroll
    for (int j = 0; j < 6; j++) {
      bf16x8 bb = *(const bf16x8*)&sKV[j * 16 + l16][k0 + quad * 8];
      acc[j] = __builtin_amdgcn_mfma_f32_16x16x32_bf16(a, bb, acc[j], 0, 0, 0);
    }
  }
  const bf16* vd = VD + ((size_t)(b * 4 + kvh) * 1024 + n0) * 96;
  bf16* oc = OC + (size_t)(b * 1024 + n0) * 1152 + h * 96;
#pragma unroll
  for (int j = 0; j < 6; j++) {
    int col = j * 16 + l16;
#pragma unroll
    for (int r = 0; r < 4; r++) {
      int row = wave * 16 + quad * 4 + r;
      float v = acc[j][r] + (float)vd[(size_t)row * 96 + col];
      oc[(size_t)row * 1152 + col] = (bf16)v;
    }
  }
}

// ---------------- launch ----------------
extern "C" void kernel_launch(void* const* d_in, const int* in_sizes, int n_in,
                              void* d_out, int out_size, void* d_ws, size_t ws_size,
                              hipStream_t stream) {
  (void)in_sizes; (void)n_in; (void)out_size; (void)ws_size;
  const void* x      = d_in[0];
  const void* wq_w   = d_in[1];
  const void* wq_b   = d_in[2];
  const void* wkv_w  = d_in[3];
  const void* wkv_b  = d_in[4];
  const void* dwc_w  = d_in[5];
  const void* dwc_b  = d_in[6];
  const void* proj_w = d_in[7];
  const void* proj_b = d_in[8];

  char* ws = (char*)d_ws;
  size_t off = 0;
  auto alloc = [&](size_t bytes) -> void* {
    void* p = ws + off;
    off = (off + bytes + 255) & ~(size_t)255;
    return p;
  };
  int*   flag   = (int*)  alloc(256);
  float* pbuf   = (float*)alloc((size_t)10368 * 4);
  float* facc   = (float*)alloc(1024 * 4);               // 512 groups x (s2,s6)
  float* scale  = (float*)alloc(512 * 4);                // [0,384) q | [384,512) k
  bf16*  wcat_t = (bf16*) alloc((size_t)2048 * 1152 * 2);// [wq_t; wkv_t; zero-pad]
  bf16*  proj_t = (bf16*) alloc((size_t)1280 * 1152 * 2);// proj_t + zero-pad rows
  bf16*  xb     = (bf16*) alloc((size_t)37748736 * 2);   // x bf16; reused: kv partials, out_comb
  float* cq     = (float*)alloc((size_t)32768 * 1920 * 4); // fused q|k|v fp32
  bf16*  kvt    = (bf16*) alloc((size_t)128 * 9216 * 2);
  bf16*  vdwc   = (bf16*) alloc((size_t)32 * 4 * 1024 * 96 * 2);
  // part aliases xb: x-bf16 content is dead after the fused GEMM's last read,
  // and k_kvred finishes reading part before k_attn writes out_comb into xb.
  float* part   = (float*)xb;                            // 37.75 MB < 75.5 MB

  k_detect<<<1, 256, 0, stream>>>((const unsigned int*)x, flag);
  k_prep<<<41, 256, 0, stream>>>(wq_b, wkv_b, dwc_w, dwc_b, proj_b, pbuf, facc, flag);
  // wq -> wcat rows [0,1152); wkv -> rows [1152,1920); zero-pad rows [1920,2048)
  k_transpose<<<dim3(36, 36), 256, 0, stream>>>(wq_w, wcat_t, 1152, 1152, 1152, flag);
  k_transpose<<<dim3(28, 36), 256, 0, stream>>>(wkv_w, wcat_t + (size_t)1152 * 1152,
                                                1152, 768, 896, flag);
  k_transpose<<<dim3(40, 36), 256, 0, stream>>>(proj_w, proj_t, 1152, 1152, 1280, flag);
  k_ingest<<<18432, 256, 0, stream>>>(x, xb, flag);

  const bf16* xbf = (const bf16*)x;

  // fused [q | kv] = x @ [wq | wkv] + b, fp32 out, focus sums fused in epilogue
  k_gemm8<<<1024, 512, 0, stream>>>(xb, xbf, 1, wcat_t, pbuf + 0, (void*)cq,
                                    32768, 2048, 1920, 1152, 1920, 0, 1, facc, flag);
  k_scales<<<2, 256, 0, stream>>>(facc, scale);

  k_kvein_part<<<1024, 256, 0, stream>>>(cq, part);
  k_kvred<<<4608, 256, 0, stream>>>(part, scale + 384, kvt);

  k_dwc<<<12288, 256, 0, stream>>>(cq, pbuf + 6912, pbuf + 5376, vdwc);
  k_attn<<<dim3(384, 16), 256, 0, stream>>>(cq, scale, kvt, vdwc, xb /* out_comb */);

  // final: out = out_comb @ proj + b -> d_out (dtype per flag), cols masked <1152
  k_gemm8<<<640, 512, 0, stream>>>(xb, nullptr, 0, proj_t, pbuf + 5760, d_out,
                                   32768, 1280, 1152, 1152, 1152, 1, 0, facc, flag);
}

// Round 6
// 833.767 us; speedup vs baseline: 1.2389x; 1.0747x over previous
//
#include <hip/hip_runtime.h>

typedef __bf16 bf16;
typedef __bf16 bf16x8 __attribute__((ext_vector_type(8)));
typedef __bf16 bf16x4 __attribute__((ext_vector_type(4)));
typedef float  f32x4  __attribute__((ext_vector_type(4)));

// Problem constants: B=32, N=1024, DIM=1152, H=12, KV=4, D=96, G=3, P=3, LS=32

static __device__ __forceinline__ float load_any(const void* p, size_t i, int isbf) {
  return isbf ? (float)((const bf16*)p)[i] : ((const float*)p)[i];
}

// async global->LDS, 16 bytes per lane. LDS dest is wave-uniform base + lane*16.
static __device__ __forceinline__ void cp16(const bf16* g, bf16* l) {
  __builtin_amdgcn_global_load_lds(
      (const __attribute__((address_space(1))) void*)g,
      (__attribute__((address_space(3))) void*)l, 16, 0, 0);
}

// ---------------- dtype detect ----------------
__global__ void k_detect(const unsigned int* __restrict__ x, int* __restrict__ flag) {
  __shared__ int cnt[256];
  unsigned int w = x[(size_t)threadIdx.x * 65536u + 123u];
  unsigned int lo = w & 0xffffu;
  int e = (int)((lo >> 7) & 0xffu);
  cnt[threadIdx.x] = (lo == 0u) || (e >= 100 && e <= 140);
  __syncthreads();
  for (int s = 128; s > 0; s >>= 1) {
    if ((int)threadIdx.x < s) cnt[threadIdx.x] += cnt[threadIdx.x + s];
    __syncthreads();
  }
  if (threadIdx.x == 0) *flag = (cnt[0] >= 128) ? 1 : 0;
}

// ---------------- small params -> fp32; zero focus accumulators ----------------
// pbuf: [0,1152) wq_b | [1152,1920) wkv_b | [1920,5376) dwc_w | [5376,5760) dwc_b
//       | [5760,6912) proj_b | [6912,10368) dwc_w transposed tap-major [9][384]
__global__ void k_prep(const void* wq_b, const void* wkv_b, const void* dwc_w,
                       const void* dwc_b, const void* proj_b,
                       float* __restrict__ pbuf, float* __restrict__ acc,
                       const int* __restrict__ flagp) {
  int isbf = *flagp;
  int i = blockIdx.x * 256 + threadIdx.x;
  if (i < 1024) acc[i] = 0.f;
  if (i >= 10368) return;
  float v;
  if (i < 1152)      v = load_any(wq_b,   i,        isbf);
  else if (i < 1920) v = load_any(wkv_b,  i - 1152, isbf);
  else if (i < 5376) v = load_any(dwc_w,  i - 1920, isbf);
  else if (i < 5760) v = load_any(dwc_b,  i - 5376, isbf);
  else if (i < 6912) v = load_any(proj_b, i - 5760, isbf);
  else {
    int r = i - 6912, tap = r / 384, c = r - tap * 384;
    v = load_any(dwc_w, (size_t)c * 9 + tap, isbf);
  }
  pbuf[i] = v;
}

// ---------------- weight transpose -> bf16 [out][in], zero-pads out rows [C,Cpad) ----------------
__global__ __launch_bounds__(256) void k_transpose(const void* __restrict__ in,
    bf16* __restrict__ out, int R, int C, int Cpad, const int* __restrict__ flagp) {
  int isbf = *flagp;
  __shared__ bf16 tile[32][33];
  int c0 = blockIdx.x * 32, r0 = blockIdx.y * 32;
  int tx = threadIdx.x & 31, ty = threadIdx.x >> 5;
  for (int i = ty; i < 32; i += 8) {
    int r = r0 + i, c = c0 + tx;
    float v = (r < R && c < C) ? load_any(in, (size_t)r * C + c, isbf) : 0.f;
    tile[i][tx] = (bf16)v;
  }
  __syncthreads();
  for (int i = ty; i < 32; i += 8) {
    int c = c0 + i, r = r0 + tx;
    if (c < Cpad && r < R) out[(size_t)c * R + r] = tile[tx][i];
  }
}

// ---------------- x ingest -> bf16 (fp32 mode only) ----------------
__global__ void k_ingest(const void* __restrict__ x, bf16* __restrict__ xb,
                         const int* __restrict__ flagp) {
  if (*flagp) return;
  size_t i = ((size_t)blockIdx.x * 256 + threadIdx.x) * 8;
  if (i >= (size_t)37748736) return;
  const float4* xf = (const float4*)((const float*)x + i);
  float4 a = xf[0], b = xf[1];
  bf16x8 o = {(bf16)a.x, (bf16)a.y, (bf16)a.z, (bf16)a.w,
              (bf16)b.x, (bf16)b.y, (bf16)b.z, (bf16)b.w};
  *(bf16x8*)(xb + i) = o;
}

// ---------------- 256x256 8-phase MFMA GEMM (T1+T2+T3+T4+T5) ----------------
// C[M,Nreal] = A[M,K] @ Bt[Npad,K]^T + bias, stores masked col<Nreal.
// 512 threads = 8 waves (2 M-halves x 4 N-quarters). BK=64, double-buffered
// 128KB LDS. R4 postmortem: bank conflicts 0 but MfmaUtil 18.7% — the wait
// ledger gave loads <1 phase of latency budget. R5 DEEP LEDGER: stage ALL
// next-tile A chunks in P1, ALL B chunks in P2 (per-wave issue order
// A0..3,B0..3). Waits:
//   P2-end  vmcnt(8): retires this tile's B r2,r3 (issued ONE TILE ago, P2)
//   tile-end vmcnt(2): retires next tile's A r0-3 + B r0,r1 (2-3 phases old)
// Cross-wave: A-half staged by 4 same-half waves (their tile-end vmcnt(2));
// LDB_Q(0) chunks = staging waves' B0,B1 (tile-end vmcnt(2)); LDB_Q(1)
// chunks = their B2,B3 (P2-end vmcnt(8)). All retire before the barrier
// preceding the consuming read. Staging addresses hoisted: source swizzle
// gcol = 8*((lane&7)^(lane>>3)) is per-lane constant; 8 pointers advance
// +64/tile. afr1 ds_reads prefetched in P1 so P2/P4 are pure-MFMA phases.
// LDS swizzle unchanged from R4 (verified, conflicts = 0): read byte addr
// XORs (l16&7)<<4; source pre-swizzled by the same involution (rule #21).
__global__ __launch_bounds__(512, 2) void k_gemm8(const bf16* __restrict__ A,
    const bf16* __restrict__ Aalt, int asel,
    const bf16* __restrict__ Bt, const float* __restrict__ bias,
    void* __restrict__ Cv, int M, int Npad, int Nreal, int K, int ldc,
    int out_mode, int focus, float* __restrict__ facc,
    const int* __restrict__ flagp) {
  __shared__ __align__(16) bf16 sA[2][256 * 64];
  __shared__ __align__(16) bf16 sB[2][256 * 64];
  __shared__ float fsh[8];
  const int t = threadIdx.x;
  const int NTN = Npad >> 8;
  const int nwg = gridDim.x;                       // % 8 == 0
  const int wg = ((int)blockIdx.x & 7) * (nwg >> 3) + ((int)blockIdx.x >> 3);
  const int n0 = (wg % NTN) << 8;
  const int m0 = (wg / NTN) << 8;
  const int wid = t >> 6, lane = t & 63, quad = lane >> 4, l16 = lane & 15;
  const int g = wid >> 2;                          // A-half / wave row group
  const int wn = (wid & 3) << 6;                   // wave col base in tile
  const int swl = (l16 & 7) << 4;                  // read-side swizzle bits
  const int flg = *flagp;
  const bf16* Asrc = (asel && flg) ? Aalt : A;
  if (t < 8) fsh[t] = 0.f;

  // ---- staging geometry (per-lane constants, hoisted out of the K-loop) ----
  const int gcol = ((lane & 7) ^ (lane >> 3)) << 3;   // swizzled source element
  const int cA  = g * 16 + (wid & 3) * 4;             // A chunks cA..cA+3
  const int cB0 = (wid >> 1) * 8 + (wid & 1) * 2;     // B chunks cB0,cB0+1 (qn0)
  const int cB1 = cB0 + 4;                            // B chunks cB1,cB1+1 (qn1)
  const bf16* pA[4];
  const bf16* pB[4];
#pragma unroll
  for (int r = 0; r < 4; r++)
    pA[r] = Asrc + (size_t)(m0 + (cA + r) * 8 + (lane >> 3)) * K + gcol;
  pB[0] = Bt + (size_t)(n0 + cB0 * 8 + (lane >> 3)) * K + gcol;
  pB[1] = pB[0] + (size_t)8 * K;
  pB[2] = Bt + (size_t)(n0 + cB1 * 8 + (lane >> 3)) * K + gcol;
  pB[3] = pB[2] + (size_t)8 * K;
  int offA[4], offB[4];
#pragma unroll
  for (int r = 0; r < 4; r++) offA[r] = (cA + r) * 512 + lane * 8;
  offB[0] = cB0 * 512 + lane * 8; offB[1] = offB[0] + 512;
  offB[2] = cB1 * 512 + lane * 8; offB[3] = offB[2] + 512;

  f32x4 acc[8][4];
  f32x4 zero = {0.f, 0.f, 0.f, 0.f};
#pragma unroll
  for (int i = 0; i < 8; i++)
#pragma unroll
    for (int j = 0; j < 4; j++) acc[i][j] = zero;

#define LDA_Q(dst, qm) do {                                                \
    _Pragma("unroll") for (int i_ = 0; i_ < 4; i_++)                       \
    _Pragma("unroll") for (int ks_ = 0; ks_ < 2; ks_++) {                  \
      int row_ = g * 128 + (qm) * 64 + i_ * 16 + l16;                      \
      int q_ = row_ * 128 + ((ks_ * 64 + quad * 16) ^ swl);                \
      dst[i_][ks_] = *(const bf16x8*)(sAc + q_); } } while (0)

#define LDB_Q(qn) do {                                                     \
    _Pragma("unroll") for (int j_ = 0; j_ < 2; j_++)                       \
    _Pragma("unroll") for (int ks_ = 0; ks_ < 2; ks_++) {                  \
      int row_ = wn + (qn) * 32 + j_ * 16 + l16;                           \
      int q_ = row_ * 128 + ((ks_ * 64 + quad * 16) ^ swl);                \
      bfr[j_][ks_] = *(const bf16x8*)(sBc + q_); } } while (0)

#define MMAQ(src, qm, qn) do {                                             \
    _Pragma("unroll") for (int ks_ = 0; ks_ < 2; ks_++)                    \
    _Pragma("unroll") for (int i_ = 0; i_ < 4; i_++)                       \
    _Pragma("unroll") for (int j_ = 0; j_ < 2; j_++)                       \
      acc[(qm) * 4 + i_][(qn) * 2 + j_] =                                  \
        __builtin_amdgcn_mfma_f32_16x16x32_bf16(src[i_][ks_], bfr[j_][ks_],\
          acc[(qm) * 4 + i_][(qn) * 2 + j_], 0, 0, 0); } while (0)

#define BAR asm volatile("s_barrier" ::: "memory")

  // prologue: stage tile 0 (A0-3 then B0-3); vmcnt(2) covers A + B qn0;
  // lgkmcnt(0) commits the fsh zero-init before the first raw barrier.
#pragma unroll
  for (int r = 0; r < 4; r++) cp16(pA[r], &sA[0][offA[r]]);
#pragma unroll
  for (int r = 0; r < 4; r++) cp16(pB[r], &sB[0][offB[r]]);
#pragma unroll
  for (int r = 0; r < 4; r++) { pA[r] += 64; pB[r] += 64; }
  asm volatile("s_waitcnt vmcnt(2) lgkmcnt(0)\ns_barrier" ::: "memory");

  bf16x8 afr0[4][2], afr1[4][2], bfr[2][2];
  const int NT = K >> 6;                 // 18 for K=1152
  int cur = 0;
  for (int tile = 0; tile < NT; ++tile) {
    const char* sAc = (const char*)&sA[cur][0];
    const char* sBc = (const char*)&sB[cur][0];
    const int nb = cur ^ 1;
    const bool stg = (tile < NT - 1);
    // P1: stage ALL next-tile A; read afr0 + B(qn0) + prefetch afr1;
    // MFMA (qm0,qn0)
    if (stg) {
#pragma unroll
      for (int r = 0; r < 4; r++) cp16(pA[r], &sA[nb][offA[r]]);
    }
    LDA_Q(afr0, 0); LDB_Q(0); LDA_Q(afr1, 1);
    __builtin_amdgcn_s_setprio(1); MMAQ(afr0, 0, 0); __builtin_amdgcn_s_setprio(0);
    BAR;
    // P2: stage ALL next-tile B; pure MFMA (qm1,qn0); end-wait vmcnt(8)
    // retires this tile's B r2,r3 (issued one full tile ago)
    if (stg) {
#pragma unroll
      for (int r = 0; r < 4; r++) cp16(pB[r], &sB[nb][offB[r]]);
#pragma unroll
      for (int r = 0; r < 4; r++) { pA[r] += 64; pB[r] += 64; }
    }
    __builtin_amdgcn_s_setprio(1); MMAQ(afr1, 1, 0); __builtin_amdgcn_s_setprio(0);
    if (stg) asm volatile("s_waitcnt vmcnt(8)\ns_barrier" ::: "memory");
    else     asm volatile("s_waitcnt vmcnt(0)\ns_barrier" ::: "memory");
    // P3: read B(qn1); MFMA (qm1,qn1)
    LDB_Q(1);
    __builtin_amdgcn_s_setprio(1); MMAQ(afr1, 1, 1); __builtin_amdgcn_s_setprio(0);
    BAR;
    // P4: pure MFMA (qm0,qn1); tile-end vmcnt(2) retires next tile's
    // A r0-3 + B r0,r1 (2-3 phases of latency budget)
    __builtin_amdgcn_s_setprio(1); MMAQ(afr0, 0, 1); __builtin_amdgcn_s_setprio(0);
    if (stg) asm volatile("s_waitcnt vmcnt(2)\ns_barrier" ::: "memory");
    else     BAR;
    cur ^= 1;
  }

  // ---------------- epilogue: bias, store (masked), fused focus sums ----------------
  const bool obf = (out_mode != 0) && (flg != 0);
#pragma unroll
  for (int J = 0; J < 4; J++) {
    int col = n0 + wn + J * 16 + l16;
    float s2 = 0.f, s6 = 0.f;
    if (col < Nreal) {
      float bv = bias[col];
#pragma unroll
      for (int I = 0; I < 8; I++) {
#pragma unroll
        for (int r = 0; r < 4; r++) {
          int row = m0 + g * 128 + I * 16 + quad * 4 + r;
          float v = acc[I][J][r] + bv;
          if (obf) ((bf16*)Cv)[(size_t)row * ldc + col] = (bf16)v;
          else     ((float*)Cv)[(size_t)row * ldc + col] = v;
          float tt = fmaxf(v, 0.f);
          float t2 = tt * tt;
          s2 += t2; s6 += t2 * t2 * t2;
        }
      }
    }
    if (focus) {
      int h = col / 96;            // uniform per fragment (16 | 96)
      if (h < 16) {
#pragma unroll
        for (int m = 1; m < 64; m <<= 1) {
          s2 += __shfl_xor(s2, m);
          s6 += __shfl_xor(s6, m);
        }
        if (lane == 0) {
          int slot = h - n0 / 96;  // block spans <=4 heads
          atomicAdd(&fsh[slot * 2],     s2);
          atomicAdd(&fsh[slot * 2 + 1], s6);
        }
      }
    }
  }
  if (focus) {
    __syncthreads();
    if (t < 4) {
      int h0 = n0 / 96;
      int h = h0 + t;
      int hmax = (n0 + 255) / 96;
      if (h <= hmax && h < 16) {
        int b = m0 >> 10;
        int gdx = (h < 12) ? (b * 12 + h) : (384 + b * 4 + (h - 12));
        atomicAdd(&facc[gdx * 2],     fsh[t * 2]);
        atomicAdd(&facc[gdx * 2 + 1], fsh[t * 2 + 1]);
      }
    }
  }
#undef LDA_Q
#undef LDB_Q
#undef MMAQ
#undef BAR
}

// focus stage 2: scale[g] = sqrt(s2/s6)
__global__ void k_scales(const float* __restrict__ acc, float* __restrict__ scale) {
  int i = blockIdx.x * 256 + threadIdx.x;
  if (i < 512) scale[i] = sqrtf(acc[i * 2] / acc[i * 2 + 1]);
}

// ---------------- kv einsum, split-K partials (k,v from fused C, ldc=1920) ----------------
__global__ __launch_bounds__(256) void k_kvein_part(const float* __restrict__ Cq,
    float* __restrict__ part) {
  int blk = blockIdx.x;                 // g*8 + c
  int g = blk >> 3, c = blk & 7;
  const float* kbase = Cq + (size_t)(g >> 2) * 1024 * 1920 + 1152 + (g & 3) * 96
                     + (size_t)c * 128 * 1920;
  const float* vbase = kbase + 384;
  __shared__ float sk[32][96];
  __shared__ float sv[32][96];
  int ty = threadIdx.x >> 4, tx = threadIdx.x & 15;
  float acc[6][6];
#pragma unroll
  for (int i = 0; i < 6; i++)
#pragma unroll
    for (int j = 0; j < 6; j++) acc[i][j] = 0.f;
  for (int nc = 0; nc < 128; nc += 32) {
    __syncthreads();
    for (int i = threadIdx.x; i < 32 * 24; i += 256) {
      int n = i / 24, d4 = (i - n * 24) * 4;
      float4 kk = *(const float4*)(kbase + (size_t)(nc + n) * 1920 + d4);
      float4 vv = *(const float4*)(vbase + (size_t)(nc + n) * 1920 + d4);
      float tv;
      tv = fmaxf(kk.x, 0.f); sk[n][d4 + 0] = tv * tv * tv;
      tv = fmaxf(kk.y, 0.f); sk[n][d4 + 1] = tv * tv * tv;
      tv = fmaxf(kk.z, 0.f); sk[n][d4 + 2] = tv * tv * tv;
      tv = fmaxf(kk.w, 0.f); sk[n][d4 + 3] = tv * tv * tv;
      sv[n][d4 + 0] = vv.x; sv[n][d4 + 1] = vv.y;
      sv[n][d4 + 2] = vv.z; sv[n][d4 + 3] = vv.w;
    }
    __syncthreads();
#pragma unroll 4
    for (int n = 0; n < 32; n++) {
      float kr[6], vr[6];
#pragma unroll
      for (int i = 0; i < 6; i++) kr[i] = sk[n][ty * 6 + i];
#pragma unroll
      for (int j = 0; j < 6; j++) vr[j] = sv[n][tx * 6 + j];
#pragma unroll
      for (int i = 0; i < 6; i++)
#pragma unroll
        for (int j = 0; j < 6; j++) acc[i][j] += kr[i] * vr[j];
    }
  }
  float* out = part + (size_t)blk * 9216;
#pragma unroll
  for (int i = 0; i < 6; i++)
#pragma unroll
    for (int j = 0; j < 6; j++)
      out[(ty * 6 + i) * 96 + tx * 6 + j] = acc[i][j];   // [dk][e]
}

// reduce 8 partials, scale, store transposed bf16: KVT[g][e][dk]
__global__ void k_kvred(const float* __restrict__ part, const float* __restrict__ sck,
                        bf16* __restrict__ KVT) {
  int t = blockIdx.x * 256 + threadIdx.x;   // over 128*9216
  if (t >= 1179648) return;
  int g = t / 9216, r = t - g * 9216;
  int dk = r / 96, e = r - dk * 96;
  const float* p = part + (size_t)g * 8 * 9216 + r;
  float s = 0.f;
#pragma unroll
  for (int c = 0; c < 8; c++) s += p[(size_t)c * 9216];
  KVT[(size_t)g * 9216 + e * 96 + dk] = (bf16)(sck[g] * s);
}

// ---------------- depthwise 3x3 conv, float4-vectorized ----------------
__global__ void k_dwc(const float* __restrict__ Cq, const float* __restrict__ pwt,
                      const float* __restrict__ pb, bf16* __restrict__ VD) {
  int idx = blockIdx.x * 256 + threadIdx.x;            // [B][KV][1024][24] float4 groups
  if (idx >= 32 * 4 * 1024 * 24) return;
  int g4 = idx % 24;
  int n  = (idx / 24) & 1023;
  int kv = (idx / (24 * 1024)) & 3;
  int b  = idx / (24 * 1024 * 4);
  int y = n >> 5, x = n & 31;
  int c0 = kv * 96 + g4 * 4;
  float4 acc = *(const float4*)(pb + c0);
  const float* vb = Cq + (size_t)b * 1024 * 1920 + 1536 + c0;
#pragma unroll
  for (int dy = -1; dy <= 1; dy++) {
    int yy = y + dy;
    if (yy < 0 || yy >= 32) continue;
#pragma unroll
    for (int dx = -1; dx <= 1; dx++) {
      int xx = x + dx;
      if (xx < 0 || xx >= 32) continue;
      float4 wv = *(const float4*)(pwt + ((dy + 1) * 3 + (dx + 1)) * 384 + c0);
      float4 vv = *(const float4*)(vb + (size_t)((yy << 5) + xx) * 1920);
      acc.x += wv.x * vv.x; acc.y += wv.y * vv.y;
      acc.z += wv.z * vv.z; acc.w += wv.w * vv.w;
    }
  }
  bf16x4 o = {(bf16)acc.x, (bf16)acc.y, (bf16)acc.z, (bf16)acc.w};
  *(bf16x4*)(VD + (size_t)idx * 4) = o;
}

// ---------------- attn: OC = focus(q) @ kv[h%4] + vdwc[h%4] ----------------
__global__ __launch_bounds__(256) void k_attn(const float* __restrict__ Cq,
    const float* __restrict__ scq, const bf16* __restrict__ KVT,
    const bf16* __restrict__ VD, bf16* __restrict__ OC) {
  int bh = blockIdx.x;
  int b = bh / 12, h = bh - b * 12;
  int kvh = h & 3;
  int n0 = blockIdx.y * 64;
  __shared__ bf16 sQ[64][104];
  __shared__ bf16 sKV[96][104];
  int t = threadIdx.x;
  float sc = scq[b * 12 + h];
  const float* qsrc = Cq + (size_t)(b * 1024 + n0) * 1920 + h * 96;
  for (int i = t; i < 64 * 24; i += 256) {
    int row = i / 24, seg = (i - row * 24) * 4;
    float4 q4 = *(const float4*)(qsrc + (size_t)row * 1920 + seg);
    bf16x4 o;
    float tv;
    tv = fmaxf(q4.x, 0.f); o[0] = (bf16)(sc * tv * tv * tv);
    tv = fmaxf(q4.y, 0.f); o[1] = (bf16)(sc * tv * tv * tv);
    tv = fmaxf(q4.z, 0.f); o[2] = (bf16)(sc * tv * tv * tv);
    tv = fmaxf(q4.w, 0.f); o[3] = (bf16)(sc * tv * tv * tv);
    *(bf16x4*)&sQ[row][seg] = o;
  }
  const bf16* kvsrc = KVT + (size_t)(b * 4 + kvh) * 9216;
  for (int i = t; i < 96 * 12; i += 256) {
    int row = i / 12, seg = (i - row * 12) * 8;
    *(bf16x8*)&sKV[row][seg] = *(const bf16x8*)(kvsrc + row * 96 + seg);
  }
  __syncthreads();
  int wave = t >> 6, lane = t & 63, quad = lane >> 4, l16 = lane & 15;
  f32x4 acc[6];
  f32x4 zero = {0.f, 0.f, 0.f, 0.f};
#pragma unroll
  for (int j = 0; j < 6; j++) acc[j] = zero;
#pragma unroll
  for (int k0 = 0; k0 < 96; k0 += 32) {
    bf16x8 a = *(const bf16x8*)&sQ[wave * 16 + l16][k0 + quad * 8];
#pragma unroll
    for (int j = 0; j < 6; j++) {
      bf16x8 bb = *(const bf16x8*)&sKV[j * 16 + l16][k0 + quad * 8];
      acc[j] = __builtin_amdgcn_mfma_f32_16x16x32_bf16(a, bb, acc[j], 0, 0, 0);
    }
  }
  const bf16* vd = VD + ((size_t)(b * 4 + kvh) * 1024 + n0) * 96;
  bf16* oc = OC + (size_t)(b * 1024 + n0) * 1152 + h * 96;
#pragma unroll
  for (int j = 0; j < 6; j++) {
    int col = j * 16 + l16;
#pragma unroll
    for (int r = 0; r < 4; r++) {
      int row = wave * 16 + quad * 4 + r;
      float v = acc[j][r] + (float)vd[(size_t)row * 96 + col];
      oc[(size_t)row * 1152 + col] = (bf16)v;
    }
  }
}

// ---------------- launch ----------------
extern "C" void kernel_launch(void* const* d_in, const int* in_sizes, int n_in,
                              void* d_out, int out_size, void* d_ws, size_t ws_size,
                              hipStream_t stream) {
  (void)in_sizes; (void)n_in; (void)out_size; (void)ws_size;
  const void* x      = d_in[0];
  const void* wq_w   = d_in[1];
  const void* wq_b   = d_in[2];
  const void* wkv_w  = d_in[3];
  const void* wkv_b  = d_in[4];
  const void* dwc_w  = d_in[5];
  const void* dwc_b  = d_in[6];
  const void* proj_w = d_in[7];
  const void* proj_b = d_in[8];

  char* ws = (char*)d_ws;
  size_t off = 0;
  auto alloc = [&](size_t bytes) -> void* {
    void* p = ws + off;
    off = (off + bytes + 255) & ~(size_t)255;
    return p;
  };
  int*   flag   = (int*)  alloc(256);
  float* pbuf   = (float*)alloc((size_t)10368 * 4);
  float* facc   = (float*)alloc(1024 * 4);               // 512 groups x (s2,s6)
  float* scale  = (float*)alloc(512 * 4);                // [0,384) q | [384,512) k
  bf16*  wcat_t = (bf16*) alloc((size_t)2048 * 1152 * 2);// [wq_t; wkv_t; zero-pad]
  bf16*  proj_t = (bf16*) alloc((size_t)1280 * 1152 * 2);// proj_t + zero-pad rows
  bf16*  xb     = (bf16*) alloc((size_t)37748736 * 2);   // x bf16; reused: kv partials, out_comb
  float* cq     = (float*)alloc((size_t)32768 * 1920 * 4); // fused q|k|v fp32
  bf16*  kvt    = (bf16*) alloc((size_t)128 * 9216 * 2);
  bf16*  vdwc   = (bf16*) alloc((size_t)32 * 4 * 1024 * 96 * 2);
  // part aliases xb: x-bf16 content is dead after the fused GEMM's last read,
  // and k_kvred finishes reading part before k_attn writes out_comb into xb.
  float* part   = (float*)xb;                            // 37.75 MB < 75.5 MB

  k_detect<<<1, 256, 0, stream>>>((const unsigned int*)x, flag);
  k_prep<<<41, 256, 0, stream>>>(wq_b, wkv_b, dwc_w, dwc_b, proj_b, pbuf, facc, flag);
  // wq -> wcat rows [0,1152); wkv -> rows [1152,1920); zero-pad rows [1920,2048)
  k_transpose<<<dim3(36, 36), 256, 0, stream>>>(wq_w, wcat_t, 1152, 1152, 1152, flag);
  k_transpose<<<dim3(28, 36), 256, 0, stream>>>(wkv_w, wcat_t + (size_t)1152 * 1152,
                                                1152, 768, 896, flag);
  k_transpose<<<dim3(40, 36), 256, 0, stream>>>(proj_w, proj_t, 1152, 1152, 1280, flag);
  k_ingest<<<18432, 256, 0, stream>>>(x, xb, flag);

  const bf16* xbf = (const bf16*)x;

  // fused [q | kv] = x @ [wq | wkv] + b, fp32 out, focus sums fused in epilogue
  k_gemm8<<<1024, 512, 0, stream>>>(xb, xbf, 1, wcat_t, pbuf + 0, (void*)cq,
                                    32768, 2048, 1920, 1152, 1920, 0, 1, facc, flag);
  k_scales<<<2, 256, 0, stream>>>(facc, scale);

  k_kvein_part<<<1024, 256, 0, stream>>>(cq, part);
  k_kvred<<<4608, 256, 0, stream>>>(part, scale + 384, kvt);

  k_dwc<<<12288, 256, 0, stream>>>(cq, pbuf + 6912, pbuf + 5376, vdwc);
  k_attn<<<dim3(384, 16), 256, 0, stream>>>(cq, scale, kvt, vdwc, xb /* out_comb */);

  // final: out = out_comb @ proj + b -> d_out (dtype per flag), cols masked <1152
  k_gemm8<<<640, 512, 0, stream>>>(xb, nullptr, 0, proj_t, pbuf + 5760, d_out,
                                   32768, 1280, 1152, 1152, 1152, 1, 0, facc, flag);
}

// Round 7
// 785.743 us; speedup vs baseline: 1.3146x; 1.0611x over previous
//
#include <hip/hip_runtime.h>

typedef __bf16 bf16;
typedef __bf16 bf16x8 __attribute__((ext_vector_type(8)));
typedef __bf16 bf16x4 __attribute__((ext_vector_type(4)));
typedef float  f32x4  __attribute__((ext_vector_type(4)));

// Problem constants: B=32, N=1024, DIM=1152, H=12, KV=4, D=96, G=3, P=3, LS=32

static __device__ __forceinline__ float load_any(const void* p, size_t i, int isbf) {
  return isbf ? (float)((const bf16*)p)[i] : ((const float*)p)[i];
}

// async global->LDS, 16 bytes per lane. LDS dest is wave-uniform base + lane*16.
static __device__ __forceinline__ void cp16(const bf16* g, bf16* l) {
  __builtin_amdgcn_global_load_lds(
      (const __attribute__((address_space(1))) void*)g,
      (__attribute__((address_space(3))) void*)l, 16, 0, 0);
}

// ---------------- dtype detect ----------------
__global__ void k_detect(const unsigned int* __restrict__ x, int* __restrict__ flag) {
  __shared__ int cnt[256];
  unsigned int w = x[(size_t)threadIdx.x * 65536u + 123u];
  unsigned int lo = w & 0xffffu;
  int e = (int)((lo >> 7) & 0xffu);
  cnt[threadIdx.x] = (lo == 0u) || (e >= 100 && e <= 140);
  __syncthreads();
  for (int s = 128; s > 0; s >>= 1) {
    if ((int)threadIdx.x < s) cnt[threadIdx.x] += cnt[threadIdx.x + s];
    __syncthreads();
  }
  if (threadIdx.x == 0) *flag = (cnt[0] >= 128) ? 1 : 0;
}

// ---------------- small params -> fp32; zero focus accumulators ----------------
// pbuf: [0,1152) wq_b | [1152,1920) wkv_b | [1920,5376) dwc_w | [5376,5760) dwc_b
//       | [5760,6912) proj_b | [6912,10368) dwc_w transposed tap-major [9][384]
__global__ void k_prep(const void* wq_b, const void* wkv_b, const void* dwc_w,
                       const void* dwc_b, const void* proj_b,
                       float* __restrict__ pbuf, float* __restrict__ acc,
                       const int* __restrict__ flagp) {
  int isbf = *flagp;
  int i = blockIdx.x * 256 + threadIdx.x;
  if (i < 1024) acc[i] = 0.f;
  if (i >= 10368) return;
  float v;
  if (i < 1152)      v = load_any(wq_b,   i,        isbf);
  else if (i < 1920) v = load_any(wkv_b,  i - 1152, isbf);
  else if (i < 5376) v = load_any(dwc_w,  i - 1920, isbf);
  else if (i < 5760) v = load_any(dwc_b,  i - 5376, isbf);
  else if (i < 6912) v = load_any(proj_b, i - 5760, isbf);
  else {
    int r = i - 6912, tap = r / 384, c = r - tap * 384;
    v = load_any(dwc_w, (size_t)c * 9 + tap, isbf);
  }
  pbuf[i] = v;
}

// ---------------- weight transpose -> bf16 [out][in], zero-pads out rows [C,Cpad) ----------------
__global__ __launch_bounds__(256) void k_transpose(const void* __restrict__ in,
    bf16* __restrict__ out, int R, int C, int Cpad, const int* __restrict__ flagp) {
  int isbf = *flagp;
  __shared__ bf16 tile[32][33];
  int c0 = blockIdx.x * 32, r0 = blockIdx.y * 32;
  int tx = threadIdx.x & 31, ty = threadIdx.x >> 5;
  for (int i = ty; i < 32; i += 8) {
    int r = r0 + i, c = c0 + tx;
    float v = (r < R && c < C) ? load_any(in, (size_t)r * C + c, isbf) : 0.f;
    tile[i][tx] = (bf16)v;
  }
  __syncthreads();
  for (int i = ty; i < 32; i += 8) {
    int c = c0 + i, r = r0 + tx;
    if (c < Cpad && r < R) out[(size_t)c * R + r] = tile[tx][i];
  }
}

// ---------------- x ingest -> bf16 (fp32 mode only) ----------------
__global__ void k_ingest(const void* __restrict__ x, bf16* __restrict__ xb,
                         const int* __restrict__ flagp) {
  if (*flagp) return;
  size_t i = ((size_t)blockIdx.x * 256 + threadIdx.x) * 8;
  if (i >= (size_t)37748736) return;
  const float4* xf = (const float4*)((const float*)x + i);
  float4 a = xf[0], b = xf[1];
  bf16x8 o = {(bf16)a.x, (bf16)a.y, (bf16)a.z, (bf16)a.w,
              (bf16)b.x, (bf16)b.y, (bf16)b.z, (bf16)b.w};
  *(bf16x8*)(xb + i) = o;
}

// ---------------- 256x256 8-phase MFMA GEMM (T1+T2+T3+T4+T5) ----------------
// C[M,Nreal] = A[M,K] @ Bt[Npad,K]^T + bias, stores masked col<Nreal.
// Structure unchanged from R5 (deep ledger, conflicts=0, MfmaUtil 25%).
// R6: out_mode=2 stores cq as BF16 with q,k PRE-CUBED in the fp32 epilogue
// (relu(v)^3 rounded once; v cols raw). Focus sums stay fp32 (unchanged).
// Halves the write stream (363->~185 MB) and all downstream reads.
__global__ __launch_bounds__(512, 2) void k_gemm8(const bf16* __restrict__ A,
    const bf16* __restrict__ Aalt, int asel,
    const bf16* __restrict__ Bt, const float* __restrict__ bias,
    void* __restrict__ Cv, int M, int Npad, int Nreal, int K, int ldc,
    int out_mode, int focus, float* __restrict__ facc,
    const int* __restrict__ flagp) {
  __shared__ __align__(16) bf16 sA[2][256 * 64];
  __shared__ __align__(16) bf16 sB[2][256 * 64];
  __shared__ float fsh[8];
  const int t = threadIdx.x;
  const int NTN = Npad >> 8;
  const int nwg = gridDim.x;                       // % 8 == 0
  const int wg = ((int)blockIdx.x & 7) * (nwg >> 3) + ((int)blockIdx.x >> 3);
  const int n0 = (wg % NTN) << 8;
  const int m0 = (wg / NTN) << 8;
  const int wid = t >> 6, lane = t & 63, quad = lane >> 4, l16 = lane & 15;
  const int g = wid >> 2;                          // A-half / wave row group
  const int wn = (wid & 3) << 6;                   // wave col base in tile
  const int swl = (l16 & 7) << 4;                  // read-side swizzle bits
  const int flg = *flagp;
  const bf16* Asrc = (asel && flg) ? Aalt : A;
  if (t < 8) fsh[t] = 0.f;

  // ---- staging geometry (per-lane constants, hoisted out of the K-loop) ----
  const int gcol = ((lane & 7) ^ (lane >> 3)) << 3;   // swizzled source element
  const int cA  = g * 16 + (wid & 3) * 4;             // A chunks cA..cA+3
  const int cB0 = (wid >> 1) * 8 + (wid & 1) * 2;     // B chunks cB0,cB0+1 (qn0)
  const int cB1 = cB0 + 4;                            // B chunks cB1,cB1+1 (qn1)
  const bf16* pA[4];
  const bf16* pB[4];
#pragma unroll
  for (int r = 0; r < 4; r++)
    pA[r] = Asrc + (size_t)(m0 + (cA + r) * 8 + (lane >> 3)) * K + gcol;
  pB[0] = Bt + (size_t)(n0 + cB0 * 8 + (lane >> 3)) * K + gcol;
  pB[1] = pB[0] + (size_t)8 * K;
  pB[2] = Bt + (size_t)(n0 + cB1 * 8 + (lane >> 3)) * K + gcol;
  pB[3] = pB[2] + (size_t)8 * K;
  int offA[4], offB[4];
#pragma unroll
  for (int r = 0; r < 4; r++) offA[r] = (cA + r) * 512 + lane * 8;
  offB[0] = cB0 * 512 + lane * 8; offB[1] = offB[0] + 512;
  offB[2] = cB1 * 512 + lane * 8; offB[3] = offB[2] + 512;

  f32x4 acc[8][4];
  f32x4 zero = {0.f, 0.f, 0.f, 0.f};
#pragma unroll
  for (int i = 0; i < 8; i++)
#pragma unroll
    for (int j = 0; j < 4; j++) acc[i][j] = zero;

#define LDA_Q(dst, qm) do {                                                \
    _Pragma("unroll") for (int i_ = 0; i_ < 4; i_++)                       \
    _Pragma("unroll") for (int ks_ = 0; ks_ < 2; ks_++) {                  \
      int row_ = g * 128 + (qm) * 64 + i_ * 16 + l16;                      \
      int q_ = row_ * 128 + ((ks_ * 64 + quad * 16) ^ swl);                \
      dst[i_][ks_] = *(const bf16x8*)(sAc + q_); } } while (0)

#define LDB_Q(qn) do {                                                     \
    _Pragma("unroll") for (int j_ = 0; j_ < 2; j_++)                       \
    _Pragma("unroll") for (int ks_ = 0; ks_ < 2; ks_++) {                  \
      int row_ = wn + (qn) * 32 + j_ * 16 + l16;                           \
      int q_ = row_ * 128 + ((ks_ * 64 + quad * 16) ^ swl);                \
      bfr[j_][ks_] = *(const bf16x8*)(sBc + q_); } } while (0)

#define MMAQ(src, qm, qn) do {                                             \
    _Pragma("unroll") for (int ks_ = 0; ks_ < 2; ks_++)                    \
    _Pragma("unroll") for (int i_ = 0; i_ < 4; i_++)                       \
    _Pragma("unroll") for (int j_ = 0; j_ < 2; j_++)                       \
      acc[(qm) * 4 + i_][(qn) * 2 + j_] =                                  \
        __builtin_amdgcn_mfma_f32_16x16x32_bf16(src[i_][ks_], bfr[j_][ks_],\
          acc[(qm) * 4 + i_][(qn) * 2 + j_], 0, 0, 0); } while (0)

#define BAR asm volatile("s_barrier" ::: "memory")

  // prologue: stage tile 0 (A0-3 then B0-3); vmcnt(2) covers A + B qn0;
  // lgkmcnt(0) commits the fsh zero-init before the first raw barrier.
#pragma unroll
  for (int r = 0; r < 4; r++) cp16(pA[r], &sA[0][offA[r]]);
#pragma unroll
  for (int r = 0; r < 4; r++) cp16(pB[r], &sB[0][offB[r]]);
#pragma unroll
  for (int r = 0; r < 4; r++) { pA[r] += 64; pB[r] += 64; }
  asm volatile("s_waitcnt vmcnt(2) lgkmcnt(0)\ns_barrier" ::: "memory");

  bf16x8 afr0[4][2], afr1[4][2], bfr[2][2];
  const int NT = K >> 6;                 // 18 for K=1152
  int cur = 0;
  for (int tile = 0; tile < NT; ++tile) {
    const char* sAc = (const char*)&sA[cur][0];
    const char* sBc = (const char*)&sB[cur][0];
    const int nb = cur ^ 1;
    const bool stg = (tile < NT - 1);
    // P1: stage ALL next-tile A; read afr0 + B(qn0) + prefetch afr1;
    // MFMA (qm0,qn0)
    if (stg) {
#pragma unroll
      for (int r = 0; r < 4; r++) cp16(pA[r], &sA[nb][offA[r]]);
    }
    LDA_Q(afr0, 0); LDB_Q(0); LDA_Q(afr1, 1);
    __builtin_amdgcn_s_setprio(1); MMAQ(afr0, 0, 0); __builtin_amdgcn_s_setprio(0);
    BAR;
    // P2: stage ALL next-tile B; pure MFMA (qm1,qn0); end-wait vmcnt(8)
    // retires this tile's B r2,r3 (issued one full tile ago)
    if (stg) {
#pragma unroll
      for (int r = 0; r < 4; r++) cp16(pB[r], &sB[nb][offB[r]]);
#pragma unroll
      for (int r = 0; r < 4; r++) { pA[r] += 64; pB[r] += 64; }
    }
    __builtin_amdgcn_s_setprio(1); MMAQ(afr1, 1, 0); __builtin_amdgcn_s_setprio(0);
    if (stg) asm volatile("s_waitcnt vmcnt(8)\ns_barrier" ::: "memory");
    else     asm volatile("s_waitcnt vmcnt(0)\ns_barrier" ::: "memory");
    // P3: read B(qn1); MFMA (qm1,qn1)
    LDB_Q(1);
    __builtin_amdgcn_s_setprio(1); MMAQ(afr1, 1, 1); __builtin_amdgcn_s_setprio(0);
    BAR;
    // P4: pure MFMA (qm0,qn1); tile-end vmcnt(2) retires next tile's
    // A r0-3 + B r0,r1 (2-3 phases of latency budget)
    __builtin_amdgcn_s_setprio(1); MMAQ(afr0, 0, 1); __builtin_amdgcn_s_setprio(0);
    if (stg) asm volatile("s_waitcnt vmcnt(2)\ns_barrier" ::: "memory");
    else     BAR;
    cur ^= 1;
  }

  // ---------------- epilogue: bias, store (masked), fused focus sums ----------------
  const bool obf = (out_mode == 1) && (flg != 0);
#pragma unroll
  for (int J = 0; J < 4; J++) {
    int col = n0 + wn + J * 16 + l16;
    float s2 = 0.f, s6 = 0.f;
    if (col < Nreal) {
      float bv = bias[col];
#pragma unroll
      for (int I = 0; I < 8; I++) {
#pragma unroll
        for (int r = 0; r < 4; r++) {
          int row = m0 + g * 128 + I * 16 + quad * 4 + r;
          float v = acc[I][J][r] + bv;
          float tt = fmaxf(v, 0.f);
          float t2 = tt * tt;
          s2 += t2; s6 += t2 * t2 * t2;
          if (out_mode == 2) {
            // cq: q,k (col<1536) stored pre-cubed relu^3; v raw. bf16.
            float ov = (col < 1536) ? tt * t2 : v;
            ((bf16*)Cv)[(size_t)row * ldc + col] = (bf16)ov;
          } else if (obf) {
            ((bf16*)Cv)[(size_t)row * ldc + col] = (bf16)v;
          } else {
            ((float*)Cv)[(size_t)row * ldc + col] = v;
          }
        }
      }
    }
    if (focus) {
      int h = col / 96;            // uniform per fragment (16 | 96)
      if (h < 16) {
#pragma unroll
        for (int m = 1; m < 64; m <<= 1) {
          s2 += __shfl_xor(s2, m);
          s6 += __shfl_xor(s6, m);
        }
        if (lane == 0) {
          int slot = h - n0 / 96;  // block spans <=4 heads
          atomicAdd(&fsh[slot * 2],     s2);
          atomicAdd(&fsh[slot * 2 + 1], s6);
        }
      }
    }
  }
  if (focus) {
    __syncthreads();
    if (t < 4) {
      int h0 = n0 / 96;
      int h = h0 + t;
      int hmax = (n0 + 255) / 96;
      if (h <= hmax && h < 16) {
        int b = m0 >> 10;
        int gdx = (h < 12) ? (b * 12 + h) : (384 + b * 4 + (h - 12));
        atomicAdd(&facc[gdx * 2],     fsh[t * 2]);
        atomicAdd(&facc[gdx * 2 + 1], fsh[t * 2 + 1]);
      }
    }
  }
#undef LDA_Q
#undef LDB_Q
#undef MMAQ
#undef BAR
}

// focus stage 2: scale[g] = sqrt(s2/s6)
__global__ void k_scales(const float* __restrict__ acc, float* __restrict__ scale) {
  int i = blockIdx.x * 256 + threadIdx.x;
  if (i < 512) scale[i] = sqrtf(acc[i * 2] / acc[i * 2 + 1]);
}

// ---------------- kv einsum, split-K partials (k^3,v bf16 from cq, ldc=1920) ----------------
__global__ __launch_bounds__(256) void k_kvein_part(const bf16* __restrict__ Cq,
    float* __restrict__ part) {
  int blk = blockIdx.x;                 // g*8 + c
  int g = blk >> 3, c = blk & 7;
  const bf16* kbase = Cq + (size_t)(g >> 2) * 1024 * 1920 + 1152 + (g & 3) * 96
                    + (size_t)c * 128 * 1920;
  const bf16* vbase = kbase + 384;
  __shared__ float sk[32][96];
  __shared__ float sv[32][96];
  int ty = threadIdx.x >> 4, tx = threadIdx.x & 15;
  float acc[6][6];
#pragma unroll
  for (int i = 0; i < 6; i++)
#pragma unroll
    for (int j = 0; j < 6; j++) acc[i][j] = 0.f;
  for (int nc = 0; nc < 128; nc += 32) {
    __syncthreads();
    for (int i = threadIdx.x; i < 32 * 12; i += 256) {
      int n = i / 12, d8 = (i - n * 12) * 8;
      bf16x8 k8 = *(const bf16x8*)(kbase + (size_t)(nc + n) * 1920 + d8);
      bf16x8 v8 = *(const bf16x8*)(vbase + (size_t)(nc + n) * 1920 + d8);
#pragma unroll
      for (int j = 0; j < 8; j++) {
        sk[n][d8 + j] = (float)k8[j];   // already relu^3 from GEMM epilogue
        sv[n][d8 + j] = (float)v8[j];
      }
    }
    __syncthreads();
#pragma unroll 4
    for (int n = 0; n < 32; n++) {
      float kr[6], vr[6];
#pragma unroll
      for (int i = 0; i < 6; i++) kr[i] = sk[n][ty * 6 + i];
#pragma unroll
      for (int j = 0; j < 6; j++) vr[j] = sv[n][tx * 6 + j];
#pragma unroll
      for (int i = 0; i < 6; i++)
#pragma unroll
        for (int j = 0; j < 6; j++) acc[i][j] += kr[i] * vr[j];
    }
  }
  float* out = part + (size_t)blk * 9216;
#pragma unroll
  for (int i = 0; i < 6; i++)
#pragma unroll
    for (int j = 0; j < 6; j++)
      out[(ty * 6 + i) * 96 + tx * 6 + j] = acc[i][j];   // [dk][e]
}

// reduce 8 partials, scale, store transposed bf16: KVT[g][e][dk]
__global__ void k_kvred(const float* __restrict__ part, const float* __restrict__ sck,
                        bf16* __restrict__ KVT) {
  int t = blockIdx.x * 256 + threadIdx.x;   // over 128*9216
  if (t >= 1179648) return;
  int g = t / 9216, r = t - g * 9216;
  int dk = r / 96, e = r - dk * 96;
  const float* p = part + (size_t)g * 8 * 9216 + r;
  float s = 0.f;
#pragma unroll
  for (int c = 0; c < 8; c++) s += p[(size_t)c * 9216];
  KVT[(size_t)g * 9216 + e * 96 + dk] = (bf16)(sck[g] * s);
}

// ---------------- depthwise 3x3 conv, vectorized (v bf16 from cq) ----------------
__global__ void k_dwc(const bf16* __restrict__ Cq, const float* __restrict__ pwt,
                      const float* __restrict__ pb, bf16* __restrict__ VD) {
  int idx = blockIdx.x * 256 + threadIdx.x;            // [B][KV][1024][24] groups of 4
  if (idx >= 32 * 4 * 1024 * 24) return;
  int g4 = idx % 24;
  int n  = (idx / 24) & 1023;
  int kv = (idx / (24 * 1024)) & 3;
  int b  = idx / (24 * 1024 * 4);
  int y = n >> 5, x = n & 31;
  int c0 = kv * 96 + g4 * 4;
  float4 acc = *(const float4*)(pb + c0);
  const bf16* vb = Cq + (size_t)b * 1024 * 1920 + 1536 + c0;
#pragma unroll
  for (int dy = -1; dy <= 1; dy++) {
    int yy = y + dy;
    if (yy < 0 || yy >= 32) continue;
#pragma unroll
    for (int dx = -1; dx <= 1; dx++) {
      int xx = x + dx;
      if (xx < 0 || xx >= 32) continue;
      float4 wv = *(const float4*)(pwt + ((dy + 1) * 3 + (dx + 1)) * 384 + c0);
      bf16x4 vv = *(const bf16x4*)(vb + (size_t)((yy << 5) + xx) * 1920);
      acc.x += wv.x * (float)vv[0]; acc.y += wv.y * (float)vv[1];
      acc.z += wv.z * (float)vv[2]; acc.w += wv.w * (float)vv[3];
    }
  }
  bf16x4 o = {(bf16)acc.x, (bf16)acc.y, (bf16)acc.z, (bf16)acc.w};
  *(bf16x4*)(VD + (size_t)idx * 4) = o;
}

// ---------------- attn: OC = sc*q3 @ kv[h%4] + vdwc[h%4] (q3 bf16 pre-cubed) ----------------
__global__ __launch_bounds__(256) void k_attn(const bf16* __restrict__ Cq,
    const float* __restrict__ scq, const bf16* __restrict__ KVT,
    const bf16* __restrict__ VD, bf16* __restrict__ OC) {
  int bh = blockIdx.x;
  int b = bh / 12, h = bh - b * 12;
  int kvh = h & 3;
  int n0 = blockIdx.y * 64;
  __shared__ bf16 sQ[64][104];
  __shared__ bf16 sKV[96][104];
  int t = threadIdx.x;
  float sc = scq[b * 12 + h];
  const bf16* qsrc = Cq + (size_t)(b * 1024 + n0) * 1920 + h * 96;
  for (int i = t; i < 64 * 12; i += 256) {
    int row = i / 12, seg = (i - row * 12) * 8;
    bf16x8 q8 = *(const bf16x8*)(qsrc + (size_t)row * 1920 + seg);
    bf16x8 o;
#pragma unroll
    for (int j = 0; j < 8; j++) o[j] = (bf16)(sc * (float)q8[j]);
    *(bf16x8*)&sQ[row][seg] = o;
  }
  const bf16* kvsrc = KVT + (size_t)(b * 4 + kvh) * 9216;
  for (int i = t; i < 96 * 12; i += 256) {
    int row = i / 12, seg = (i - row * 12) * 8;
    *(bf16x8*)&sKV[row][seg] = *(const bf16x8*)(kvsrc + row * 96 + seg);
  }
  __syncthreads();
  int wave = t >> 6, lane = t & 63, quad = lane >> 4, l16 = lane & 15;
  f32x4 acc[6];
  f32x4 zero = {0.f, 0.f, 0.f, 0.f};
#pragma unroll
  for (int j = 0; j < 6; j++) acc[j] = zero;
#pragma unroll
  for (int k0 = 0; k0 < 96; k0 += 32) {
    bf16x8 a = *(const bf16x8*)&sQ[wave * 16 + l16][k0 + quad * 8];
#pragma unroll
    for (int j = 0; j < 6; j++) {
      bf16x8 bb = *(const bf16x8*)&sKV[j * 16 + l16][k0 + quad * 8];
      acc[j] = __builtin_amdgcn_mfma_f32_16x16x32_bf16(a, bb, acc[j], 0, 0, 0);
    }
  }
  const bf16* vd = VD + ((size_t)(b * 4 + kvh) * 1024 + n0) * 96;
  bf16* oc = OC + (size_t)(b * 1024 + n0) * 1152 + h * 96;
#pragma unroll
  for (int j = 0; j < 6; j++) {
    int col = j * 16 + l16;
#pragma unroll
    for (int r = 0; r < 4; r++) {
      int row = wave * 16 + quad * 4 + r;
      float v = acc[j][r] + (float)vd[(size_t)row * 96 + col];
      oc[(size_t)row * 1152 + col] = (bf16)v;
    }
  }
}

// ---------------- launch ----------------
extern "C" void kernel_launch(void* const* d_in, const int* in_sizes, int n_in,
                              void* d_out, int out_size, void* d_ws, size_t ws_size,
                              hipStream_t stream) {
  (void)in_sizes; (void)n_in; (void)out_size; (void)ws_size;
  const void* x      = d_in[0];
  const void* wq_w   = d_in[1];
  const void* wq_b   = d_in[2];
  const void* wkv_w  = d_in[3];
  const void* wkv_b  = d_in[4];
  const void* dwc_w  = d_in[5];
  const void* dwc_b  = d_in[6];
  const void* proj_w = d_in[7];
  const void* proj_b = d_in[8];

  char* ws = (char*)d_ws;
  size_t off = 0;
  auto alloc = [&](size_t bytes) -> void* {
    void* p = ws + off;
    off = (off + bytes + 255) & ~(size_t)255;
    return p;
  };
  int*   flag   = (int*)  alloc(256);
  float* pbuf   = (float*)alloc((size_t)10368 * 4);
  float* facc   = (float*)alloc(1024 * 4);               // 512 groups x (s2,s6)
  float* scale  = (float*)alloc(512 * 4);                // [0,384) q | [384,512) k
  bf16*  wcat_t = (bf16*) alloc((size_t)2048 * 1152 * 2);// [wq_t; wkv_t; zero-pad]
  bf16*  proj_t = (bf16*) alloc((size_t)1280 * 1152 * 2);// proj_t + zero-pad rows
  bf16*  xb     = (bf16*) alloc((size_t)37748736 * 2);   // x bf16; reused: kv partials, out_comb
  bf16*  cq     = (bf16*) alloc((size_t)32768 * 1920 * 2); // fused q3|k3|v bf16
  bf16*  kvt    = (bf16*) alloc((size_t)128 * 9216 * 2);
  bf16*  vdwc   = (bf16*) alloc((size_t)32 * 4 * 1024 * 96 * 2);
  // part aliases xb: x-bf16 content is dead after the fused GEMM's last read,
  // and k_kvred finishes reading part before k_attn writes out_comb into xb.
  float* part   = (float*)xb;                            // 37.75 MB < 75.5 MB

  k_detect<<<1, 256, 0, stream>>>((const unsigned int*)x, flag);
  k_prep<<<41, 256, 0, stream>>>(wq_b, wkv_b, dwc_w, dwc_b, proj_b, pbuf, facc, flag);
  // wq -> wcat rows [0,1152); wkv -> rows [1152,1920); zero-pad rows [1920,2048)
  k_transpose<<<dim3(36, 36), 256, 0, stream>>>(wq_w, wcat_t, 1152, 1152, 1152, flag);
  k_transpose<<<dim3(28, 36), 256, 0, stream>>>(wkv_w, wcat_t + (size_t)1152 * 1152,
                                                1152, 768, 896, flag);
  k_transpose<<<dim3(40, 36), 256, 0, stream>>>(proj_w, proj_t, 1152, 1152, 1280, flag);
  k_ingest<<<18432, 256, 0, stream>>>(x, xb, flag);

  const bf16* xbf = (const bf16*)x;

  // fused [q | kv] = x @ [wq | wkv] + b; cq bf16 (q,k pre-cubed), focus fused
  k_gemm8<<<1024, 512, 0, stream>>>(xb, xbf, 1, wcat_t, pbuf + 0, (void*)cq,
                                    32768, 2048, 1920, 1152, 1920, 2, 1, facc, flag);
  k_scales<<<2, 256, 0, stream>>>(facc, scale);

  k_kvein_part<<<1024, 256, 0, stream>>>(cq, part);
  k_kvred<<<4608, 256, 0, stream>>>(part, scale + 384, kvt);

  k_dwc<<<12288, 256, 0, stream>>>(cq, pbuf + 6912, pbuf + 5376, vdwc);
  k_attn<<<dim3(384, 16), 256, 0, stream>>>(cq, scale, kvt, vdwc, xb /* out_comb */);

  // final: out = out_comb @ proj + b -> d_out (dtype per flag), cols masked <1152
  k_gemm8<<<640, 512, 0, stream>>>(xb, nullptr, 0, proj_t, pbuf + 5760, d_out,
                                   32768, 1280, 1152, 1152, 1152, 1, 0, facc, flag);
}